// Round 13
// baseline (382.613 us; speedup 1.0000x reference)
//
#include <hip/hip_runtime.h>

// B=8, C=192, H=W=128, NH=6, HD=32, WS=8, N=64 tokens/window. 2048 windows.
// Round 13: round-11 structure (512 thr, 73.7 KB LDS, 2 blocks/CU, split proj)
// + x pre-packed to bf16 window slabs (exact swizzled RA image) by xprep_kernel.
// Slabs alias the yb buffer: block wid reads slab wid at P1, overwrites it with
// y at P5b (block-private -> safe). Fused P1 = raw 24 KB contiguous copy; every
// x byte leaves HBM once, full-line, fixing the x L2-thrash found in round 12.
#define SCALEQ 0.17677669529663687f   // 32^-0.5

typedef __bf16 bf16x8 __attribute__((ext_vector_type(8)));
typedef __bf16 bf16x2 __attribute__((ext_vector_type(2)));
typedef float f32x4 __attribute__((ext_vector_type(4)));
typedef float f32x2 __attribute__((ext_vector_type(2)));

__device__ __forceinline__ float bflo(unsigned int u) { return __uint_as_float(u << 16); }
__device__ __forceinline__ float bfhi(unsigned int u) { return __uint_as_float(u & 0xffff0000u); }
__device__ __forceinline__ f32x2 b2x2(unsigned int u) {
    f32x2 r; r[0] = bflo(u); r[1] = bfhi(u); return r;
}
// native RNE converts (v_cvt_pk_bf16_f32)
__device__ __forceinline__ unsigned short f2b(float f) {
    return __builtin_bit_cast(unsigned short, (__bf16)f);
}
__device__ __forceinline__ unsigned int pk2(float a, float b) {
    bf16x2 v; v[0] = (__bf16)a; v[1] = (__bf16)b;
    return __builtin_bit_cast(unsigned int, v);
}

// LDS: 3 x 24 KB regions (swizzle byte ^= (row&7)<<4), time-multiplexed:
//  RA 0      xs[64][192] (P1-hoist) | q[64][192] (P2-P3) | v_n[64][192] (P3b-P4)
//  RB 24576  k[64][192]  (P2-P3)    | v_t[192][64] (P3b-P5)
//  RC 49152  o[64][192]  (P3-P4)    | y[64][192]  (P5-)
#define RA     0
#define RB     24576
#define RC     49152
#define LDS_BYTES 73728

// d_ws layout (bytes):
//  [0]      qkv weights bf16 [576][192] (q rows pre-scaled)   221184 B
//  [221184] proj weights bf16 [192][192]                       73728 B
//  [294912] bias2 f32 [6][64][64]                              98304 B
//  [393216] slab buffer [2048][24576 B]: xprep writes x-slabs; fused reads slab
//           wid at P1 then overwrites it with y at P5b; proj reads y slabs.
#define WS_WQKV_ELEMS 110592
#define WS_WP_OFF_EL  110592
#define WS_B2_OFF_B   294912
#define WS_SLAB_OFF_B 393216
#define WS_TOTAL_B    50724864

__device__ __forceinline__ bf16x8 ldsf(const char* p) {
    uint4 u = *(const uint4*)p;
    return __builtin_bit_cast(bf16x8, u);
}
__device__ __forceinline__ bf16x8 gldf(const unsigned short* p) {
    uint4 u = *(const uint4*)p;
    return __builtin_bit_cast(bf16x8, u);
}

// ---- prep kernel: weights f32->bf16 (q pre-scaled) + bias2 table. 672 blocks ----
__global__ void prep_kernel(const float* __restrict__ QKw, const float* __restrict__ Vw,
                            const float* __restrict__ Pw,
                            const float* __restrict__ Mw1, const float* __restrict__ Mb1,
                            const float* __restrict__ Mw2, const float* __restrict__ Mb2,
                            unsigned short* __restrict__ wsb, float* __restrict__ b2) {
    int gid = blockIdx.x * 256 + threadIdx.x;      // 0 .. 172031
    if (gid < WS_WQKV_ELEMS) {
        int r = gid / 192, c = gid - r * 192;
        float v = (r < 384) ? QKw[r * 192 + c] : Vw[(r - 384) * 192 + c];
        if (r < 192) v *= SCALEQ;
        wsb[gid] = f2b(v);
    } else if (gid < 147456) {
        int j = gid - WS_WQKV_ELEMS;
        wsb[WS_WP_OFF_EL + j] = f2b(Pw[j]);
    } else {
        int i = gid - 147456;                       // 0 .. 24575
        int h = i >> 12, n = (i >> 6) & 63, m = i & 63;
        float dy = (float)((n >> 3) - (m >> 3));
        float dx = (float)((n & 7) - (m & 7));
        float f0 = copysignf(log1pf(fabsf(dy)), dy);
        float f1 = copysignf(log1pf(fabsf(dx)), dx);
        float a = Mb2[h];
        for (int u = 0; u < 256; ++u) {
            float hv = fmaxf(f0 * Mw1[u] + f1 * Mw1[256 + u] + Mb1[u], 0.0f);
            a = fmaf(hv, Mw2[u * 6 + h], a);
        }
        b2[i] = a;
    }
}

// ---- xprep: x fp32 -> bf16 window slabs (exact swizzled RA image) ----
// block = (b, wy, wxg of 4 windows): every x-line (128B) read exactly once.
__global__ __launch_bounds__(256)
void xprep_kernel(const float* __restrict__ x, char* __restrict__ xw) {
    int blk = blockIdx.x;                  // 0..511
    int b = blk >> 6, wy = (blk >> 2) & 15, wxg = blk & 3;
    const float* xb = x + (size_t)b * 192 * 16384;
    #pragma unroll 4
    for (int i = 0; i < 48; ++i) {
        int idx = threadIdx.x + 256 * i;   // 0..12287
        int c = idx >> 6, rem = idx & 63;
        int r = rem >> 3, g = rem & 7;     // g = float4 group; px32 = g*4
        float4 v4 = *(const float4*)(xb + c * 16384 + (wy * 8 + r) * 128 + wxg * 32 + g * 4);
        int wx  = wxg * 4 + (g >> 1);
        int wid = (b << 8) | (wy << 4) | wx;
        char* slab = xw + (size_t)wid * 24576;
        int n0 = r * 8 + (g & 1) * 4;
        unsigned short sv[4] = {f2b(v4.x), f2b(v4.y), f2b(v4.z), f2b(v4.w)};
        #pragma unroll
        for (int e = 0; e < 4; ++e) {
            int n = n0 + e;
            *(unsigned short*)(slab + ((n * 384 + c * 2) ^ ((n & 7) << 4))) = sv[e];
        }
    }
}

__global__ __launch_bounds__(512, 4)
void fused_win_attn(const float* __restrict__ x,
                    const float* __restrict__ Vb, const float* __restrict__ QKb,
                    const float* __restrict__ Pb,
                    const unsigned short* __restrict__ wqkv,   // bf16 [576][192]
                    const unsigned short* __restrict__ wp,     // bf16 [192][192]
                    const float* __restrict__ bias2,           // f32 [6][64][64]
                    char* __restrict__ slabs,                  // [2048][24576] x-in / y-out
                    float* __restrict__ out,
                    int split)
{
    extern __shared__ char smem[];
    const int t   = threadIdx.x;
    const int wv  = t >> 6;           // wave 0..7
    const int l15 = t & 15;
    const int l4  = (t >> 4) & 3;

    const int wid = ((blockIdx.x & 7) << 8) | (blockIdx.x >> 3);
    const int b   = wid >> 8;
    const int wy  = (wid >> 4) & 15;
    const int wx  = wid & 15;
    const int y0  = wy * 8, x0 = wx * 8;

    const f32x4 zz = {0.0f, 0.0f, 0.0f, 0.0f};

    // ---- P1: stage x slab -> RA ----
    if (split) {
        const char* slab = slabs + (size_t)wid * 24576;
        #pragma unroll
        for (int i = 0; i < 3; ++i) {
            int idx = t + 512 * i;               // 1536 uint4 chunks
            uint4 v = *(const uint4*)(slab + idx * 16);
            *(uint4*)(smem + RA + idx * 16) = v;
        }
    } else {
        const float* xb = x + (size_t)b * 192 * 16384;
        #pragma unroll
        for (int i = 0; i < 6; ++i) {
            int idx = t + 512 * i;
            int c = idx >> 4, sub = idx & 15;
            int r = sub >> 1, hf = sub & 1;
            float4 v4 = *(const float4*)(xb + c * 16384 + (y0 + r) * 128 + x0 + hf * 4);
            int n0 = r * 8 + hf * 4;
            unsigned short sv[4] = {f2b(v4.x), f2b(v4.y), f2b(v4.z), f2b(v4.w)};
            #pragma unroll
            for (int e = 0; e < 4; ++e) {
                int n = n0 + e;
                *(unsigned short*)(smem + RA + ((n * 384 + c * 2) ^ ((n & 7) << 4))) = sv[e];
            }
        }
    }
    __syncthreads();

    // ---- P2: qkv GEMM. wave (wcol, wrow): cols [48*wcol,+48) per tensor, toks [32*wrow,+32) ----
    const int wcol = wv & 3, wrow = wv >> 2;
    unsigned int vp[3][2][2];          // packed v held across conv: [j][mtl][tok-pair]
    {
        bf16x8 afr[6][2];
        #pragma unroll
        for (int ks = 0; ks < 6; ++ks)
            #pragma unroll
            for (int mtl = 0; mtl < 2; ++mtl) {
                int row = (wrow * 2 + mtl) * 16 + l15;
                afr[ks][mtl] = ldsf(smem + RA + ((row * 384 + ks * 64 + l4 * 16) ^ ((row & 7) << 4)));
            }
        __syncthreads();

        auto gemm3 = [&](int obase, f32x4 acc[3][2]) {
            bf16x8 bw[3][6];
            #pragma unroll
            for (int j = 0; j < 3; ++j) {
                const unsigned short* wr = wqkv + (size_t)(obase + j * 16 + l15) * 192 + l4 * 8;
                #pragma unroll
                for (int ks = 0; ks < 6; ++ks) bw[j][ks] = gldf(wr + ks * 32);
            }
            #pragma unroll
            for (int j = 0; j < 3; ++j) { acc[j][0] = zz; acc[j][1] = zz; }
            #pragma unroll
            for (int ks = 0; ks < 6; ++ks)
                #pragma unroll
                for (int j = 0; j < 3; ++j)
                    #pragma unroll
                    for (int mtl = 0; mtl < 2; ++mtl)
                        acc[j][mtl] = __builtin_amdgcn_mfma_f32_16x16x32_bf16(afr[ks][mtl], bw[j][ks], acc[j][mtl], 0, 0, 0);
        };

        // chunk 0: q -> region A (weights pre-scaled; bias scaled here)
        {
            f32x4 acc[3][2];
            gemm3(wcol * 48, acc);
            #pragma unroll
            for (int j = 0; j < 3; ++j) {
                int och = wcol * 48 + j * 16 + l15;
                float bv = QKb[och] * SCALEQ;
                #pragma unroll
                for (int mtl = 0; mtl < 2; ++mtl)
                    #pragma unroll
                    for (int rr = 0; rr < 4; ++rr) {
                        int tok = (wrow * 2 + mtl) * 16 + l4 * 4 + rr;
                        *(unsigned short*)(smem + RA + ((tok * 384 + och * 2) ^ ((tok & 7) << 4)))
                            = f2b(acc[j][mtl][rr] + bv);
                    }
            }
        }
        // chunk 1: k -> region B
        {
            f32x4 acc[3][2];
            gemm3(192 + wcol * 48, acc);
            #pragma unroll
            for (int j = 0; j < 3; ++j) {
                int ch = wcol * 48 + j * 16 + l15;
                float bv = QKb[192 + ch];
                #pragma unroll
                for (int mtl = 0; mtl < 2; ++mtl)
                    #pragma unroll
                    for (int rr = 0; rr < 4; ++rr) {
                        int tok = (wrow * 2 + mtl) * 16 + l4 * 4 + rr;
                        *(unsigned short*)(smem + RB + ((tok * 384 + ch * 2) ^ ((tok & 7) << 4)))
                            = f2b(acc[j][mtl][rr] + bv);
                    }
            }
        }
        // chunk 2: v -> registers (packed bf16 pairs along tok)
        {
            f32x4 acc[3][2];
            gemm3(384 + wcol * 48, acc);
            #pragma unroll
            for (int j = 0; j < 3; ++j) {
                int ch = wcol * 48 + j * 16 + l15;
                float bv = Vb[ch];
                #pragma unroll
                for (int mtl = 0; mtl < 2; ++mtl) {
                    vp[j][mtl][0] = pk2(acc[j][mtl][0] + bv, acc[j][mtl][1] + bv);
                    vp[j][mtl][1] = pk2(acc[j][mtl][2] + bv, acc[j][mtl][3] + bv);
                }
            }
        }
    }
    __syncthreads();

    // ---- P3: 8x8 circular conv q(A) x k(B) -> o(C). 384 threads, f32x2 packed ----
    if (t < 384) {
        const int rn = t / 48, cc = t % 48;
        const int c0b = cc * 8;               // byte offset of 4-ch chunk
        f32x2 acc[8][2];
        #pragma unroll
        for (int cn = 0; cn < 8; ++cn) {
            acc[cn][0] = (f32x2){0.0f, 0.0f};
            acc[cn][1] = (f32x2){0.0f, 0.0f};
        }
        #pragma unroll
        for (int kh = 0; kh < 2; ++kh) {
            uint2 karr[32];
            #pragma unroll
            for (int m = 0; m < 32; ++m) {
                int row = kh * 32 + m;
                karr[m] = *(const uint2*)(smem + RB + ((row * 384 + c0b) ^ ((row & 7) << 4)));
            }
            #pragma unroll
            for (int mrl = 0; mrl < 4; ++mrl) {
                const int mr = kh * 4 + mrl;
                f32x2 kf[8][2];
                #pragma unroll
                for (int mc = 0; mc < 8; ++mc) {
                    uint2 kv = karr[mrl * 8 + mc];
                    kf[mc][0] = b2x2(kv.x); kf[mc][1] = b2x2(kv.y);
                }
                const int npr = (rn - mr) & 7;
                #pragma unroll
                for (int npc = 0; npc < 8; ++npc) {
                    int np = npr * 8 + npc;
                    uint2 qv = *(const uint2*)(smem + RA + ((np * 384 + c0b) ^ ((np & 7) << 4)));
                    f32x2 qf0 = b2x2(qv.x), qf1 = b2x2(qv.y);
                    #pragma unroll
                    for (int mc = 0; mc < 8; ++mc) {
                        int cn = (npc + mc) & 7;
                        acc[cn][0] = qf0 * kf[mc][0] + acc[cn][0];
                        acc[cn][1] = qf1 * kf[mc][1] + acc[cn][1];
                    }
                }
            }
        }
        #pragma unroll
        for (int cn = 0; cn < 8; ++cn) {
            int n = rn * 8 + cn;
            uint2 pk;
            pk.x = pk2(acc[cn][0][0], acc[cn][0][1]);
            pk.y = pk2(acc[cn][1][0], acc[cn][1][1]);
            *(uint2*)(smem + RC + ((n * 384 + c0b) ^ ((n & 7) << 4))) = pk;
        }
    }
    __syncthreads();

    // ---- P3b: write held v regs -> v_n (A, over q) and v_t (B, over k) ----
    {
        #pragma unroll
        for (int j = 0; j < 3; ++j) {
            int ch = wcol * 48 + j * 16 + l15;
            #pragma unroll
            for (int mtl = 0; mtl < 2; ++mtl)
                #pragma unroll
                for (int pp = 0; pp < 2; ++pp) {
                    unsigned int pk = vp[j][mtl][pp];
                    int tok0 = (wrow * 2 + mtl) * 16 + l4 * 4 + pp * 2;
                    *(unsigned int*)(smem + RB + ((ch * 128 + tok0 * 2) ^ ((ch & 7) << 4))) = pk;
                    *(unsigned short*)(smem + RA + ((tok0 * 384 + ch * 2) ^ ((tok0 & 7) << 4)))
                        = (unsigned short)(pk & 0xffffu);
                    *(unsigned short*)(smem + RA + (((tok0 + 1) * 384 + ch * 2) ^ (((tok0 + 1) & 7) << 4)))
                        = (unsigned short)(pk >> 16);
                }
        }
    }
    __syncthreads();

    // ---- P4: S^T = mfma(v_n, o) + bias2, softmax over m, P packed in regs ----
    unsigned int pv[3][4][2];              // [unit][mt][pair]: P[n=l15-col][m]
    {
        #pragma unroll
        for (int i = 0; i < 3; ++i) {
            int u = wv * 3 + i;
            int h = u >> 2, nt = u & 3;
            int brow = nt * 16 + l15;
            bf16x8 ofr = ldsf(smem + RC + ((brow * 384 + h * 64 + l4 * 16) ^ ((brow & 7) << 4)));
            int n = nt * 16 + l15;
            const float* bp = bias2 + ((h * 64 + n) << 6) + l4 * 4;
            float s[4][4];
            #pragma unroll
            for (int mt = 0; mt < 4; ++mt) {
                int arow = mt * 16 + l15;
                bf16x8 vfr = ldsf(smem + RA + ((arow * 384 + h * 64 + l4 * 16) ^ ((arow & 7) << 4)));
                f32x4 a = __builtin_amdgcn_mfma_f32_16x16x32_bf16(vfr, ofr, zz, 0, 0, 0);
                float4 bb = *(const float4*)(bp + mt * 16);
                s[mt][0] = a[0] + bb.x; s[mt][1] = a[1] + bb.y;
                s[mt][2] = a[2] + bb.z; s[mt][3] = a[3] + bb.w;
            }
            float m0 = s[0][0];
            #pragma unroll
            for (int mt = 0; mt < 4; ++mt)
                #pragma unroll
                for (int rr = 0; rr < 4; ++rr) m0 = fmaxf(m0, s[mt][rr]);
            m0 = fmaxf(m0, __shfl_xor(m0, 16));
            m0 = fmaxf(m0, __shfl_xor(m0, 32));
            float sm = 0.0f;
            #pragma unroll
            for (int mt = 0; mt < 4; ++mt)
                #pragma unroll
                for (int rr = 0; rr < 4; ++rr) {
                    float p = __expf(s[mt][rr] - m0);
                    s[mt][rr] = p; sm += p;
                }
            sm += __shfl_xor(sm, 16);
            sm += __shfl_xor(sm, 32);
            float inv = 1.0f / sm;
            #pragma unroll
            for (int mt = 0; mt < 4; ++mt) {
                pv[i][mt][0] = pk2(s[mt][0] * inv, s[mt][1] * inv);
                pv[i][mt][1] = pk2(s[mt][2] * inv, s[mt][3] * inv);
            }
        }
    }
    __syncthreads();   // all units done reading o -> region C reusable

    // ---- P5: Y = mfma(P, v_t) -> y in RC ----
    {
        #pragma unroll
        for (int i = 0; i < 3; ++i) {
            int u = wv * 3 + i;
            int h = u >> 2, nt = u & 3;
            bf16x8 pafr[2];
            #pragma unroll
            for (int ks = 0; ks < 2; ++ks) {
                unsigned int au[4];
                #pragma unroll
                for (int p = 0; p < 4; ++p) {
                    int srcl4 = (2 * l4 + (p >> 1)) & 3;
                    int src = srcl4 * 16 + l15;
                    unsigned int v0 = (unsigned int)__shfl((int)pv[i][2 * ks][p & 1], src, 64);
                    unsigned int v1 = (unsigned int)__shfl((int)pv[i][2 * ks + 1][p & 1], src, 64);
                    au[p] = (l4 & 2) ? v1 : v0;
                }
                uint4 u4 = {au[0], au[1], au[2], au[3]};
                pafr[ks] = __builtin_bit_cast(bf16x8, u4);
            }
            f32x4 acc[2];
            acc[0] = zz; acc[1] = zz;
            #pragma unroll
            for (int dt = 0; dt < 2; ++dt)
                #pragma unroll
                for (int ks = 0; ks < 2; ++ks) {
                    int drow = h * 32 + dt * 16 + l15;
                    bf16x8 vtf = ldsf(smem + RB + ((drow * 128 + ks * 64 + l4 * 16) ^ ((drow & 7) << 4)));
                    acc[dt] = __builtin_amdgcn_mfma_f32_16x16x32_bf16(pafr[ks], vtf, acc[dt], 0, 0, 0);
                }
            #pragma unroll
            for (int dt = 0; dt < 2; ++dt)
                #pragma unroll
                for (int rr = 0; rr < 4; ++rr) {
                    int tok = nt * 16 + l4 * 4 + rr;
                    int ch  = h * 32 + dt * 16 + l15;
                    *(unsigned short*)(smem + RC + ((tok * 384 + ch * 2) ^ ((tok & 7) << 4))) = f2b(acc[dt][rr]);
                }
        }
    }
    __syncthreads();

    if (split) {
        // ---- P5b: raw copy RC (24 KB, swizzled) -> slab wid (over x image) ----
        char* ybw = slabs + (size_t)wid * 24576;
        #pragma unroll
        for (int c = 0; c < 3; ++c) {
            int idx = t + 512 * c;               // 0..1535 uint4 chunks
            uint4 v = *(const uint4*)(smem + RC + idx * 16);
            *(uint4*)(ybw + idx * 16) = v;
        }
        return;
    }

    // ---- P6 (fallback only): proj OUT^T[oc][tok] = Pw . y^T ----
    {
        const int wc = wv & 3, wr = wv >> 2;
        bf16x8 wfr[3][6];
        #pragma unroll
        for (int jt = 0; jt < 3; ++jt) {
            int oc = wc * 48 + jt * 16;
            const unsigned short* wr_ = wp + (size_t)(oc + l15) * 192 + l4 * 8;
            #pragma unroll
            for (int ks = 0; ks < 6; ++ks) wfr[jt][ks] = gldf(wr_ + ks * 32);
        }
        f32x4 acc[3][2];
        #pragma unroll
        for (int jt = 0; jt < 3; ++jt) { acc[jt][0] = zz; acc[jt][1] = zz; }

        #pragma unroll
        for (int ks = 0; ks < 6; ++ks) {
            bf16x8 bfr[2];
            #pragma unroll
            for (int ntl = 0; ntl < 2; ++ntl) {
                int tok = (wr * 2 + ntl) * 16 + l15;
                bfr[ntl] = ldsf(smem + RC + ((tok * 384 + ks * 64 + l4 * 16) ^ ((tok & 7) << 4)));
            }
            #pragma unroll
            for (int jt = 0; jt < 3; ++jt)
                #pragma unroll
                for (int ntl = 0; ntl < 2; ++ntl)
                    acc[jt][ntl] = __builtin_amdgcn_mfma_f32_16x16x32_bf16(wfr[jt][ks], bfr[ntl], acc[jt][ntl], 0, 0, 0);
        }
        #pragma unroll
        for (int jt = 0; jt < 3; ++jt)
            #pragma unroll
            for (int rr = 0; rr < 4; ++rr) {
                int oc = wc * 48 + jt * 16 + l4 * 4 + rr;
                float pb = Pb[oc];
                float* obase = out + (size_t)(b * 192 + oc) * 16384;
                #pragma unroll
                for (int ntl = 0; ntl < 2; ++ntl) {
                    int tok = (wr * 2 + ntl) * 16 + l15;
                    obase[(y0 + (tok >> 3)) * 128 + x0 + (tok & 7)] = acc[jt][ntl][rr] + pb;
                }
            }
    }
}

// ---- proj kernel (split mode): one output row y per block, full-line writes ----
__global__ __launch_bounds__(256)
void proj_kernel(const char* __restrict__ yb,             // raw [2048][24576]
                 const unsigned short* __restrict__ wp,   // bf16 [192][192]
                 const float* __restrict__ Pb,
                 float* __restrict__ out)
{
    extern __shared__ char smem[];                        // ya[128 px][192 ch] bf16 swizzled
    const int t   = threadIdx.x;
    const int wv  = t >> 6;          // wave 0..3
    const int l15 = t & 15;
    const int l4  = (t >> 4) & 3;

    const int by = blockIdx.x;       // 0..1023
    const int b  = by >> 7;
    const int y  = by & 127;
    const int wy = y >> 3, row = y & 7;

    const f32x4 zz = {0.0f, 0.0f, 0.0f, 0.0f};

    // stage raw swizzled slabs: window wx's toks row*8..row*8+7 = contiguous 3072 B.
    #pragma unroll
    for (int k = 0; k < 12; ++k) {
        int i = t + 256 * k;         // 0..3071 = (px, 16B-chunk cb)
        int px = i / 24, cb = i % 24;
        int wx = px >> 3, col = px & 7;
        const char* src = yb + (size_t)(((b * 16 + wy) * 16 + wx)) * 24576
                        + row * 3072 + col * 384 + cb * 16;
        uint4 v = *(const uint4*)src;
        *(uint4*)(smem + px * 384 + cb * 16) = v;
    }
    __syncthreads();

    bf16x8 wfr[3][6];
    #pragma unroll
    for (int jt = 0; jt < 3; ++jt) {
        int oc = wv * 48 + jt * 16;
        const unsigned short* wr_ = wp + (size_t)(oc + l15) * 192 + l4 * 8;
        #pragma unroll
        for (int ks = 0; ks < 6; ++ks) wfr[jt][ks] = gldf(wr_ + ks * 32);
    }
    #pragma unroll
    for (int half = 0; half < 2; ++half) {
        f32x4 acc[3][4];
        #pragma unroll
        for (int jt = 0; jt < 3; ++jt)
            #pragma unroll
            for (int ntl = 0; ntl < 4; ++ntl) acc[jt][ntl] = zz;
        #pragma unroll
        for (int ks = 0; ks < 6; ++ks) {
            bf16x8 bfr[4];
            #pragma unroll
            for (int ntl = 0; ntl < 4; ++ntl) {
                int px = (half * 4 + ntl) * 16 + l15;
                bfr[ntl] = ldsf(smem + ((px * 384 + ks * 64 + l4 * 16) ^ ((px & 7) << 4)));
            }
            #pragma unroll
            for (int jt = 0; jt < 3; ++jt)
                #pragma unroll
                for (int ntl = 0; ntl < 4; ++ntl)
                    acc[jt][ntl] = __builtin_amdgcn_mfma_f32_16x16x32_bf16(wfr[jt][ks], bfr[ntl], acc[jt][ntl], 0, 0, 0);
        }
        #pragma unroll
        for (int jt = 0; jt < 3; ++jt)
            #pragma unroll
            for (int rr = 0; rr < 4; ++rr) {
                int oc = wv * 48 + jt * 16 + l4 * 4 + rr;
                float pb = Pb[oc];
                float* op = out + ((size_t)(b * 192 + oc) * 128 + y) * 128;
                #pragma unroll
                for (int ntl = 0; ntl < 4; ++ntl) {
                    int px = (half * 4 + ntl) * 16 + l15;
                    op[px] = acc[jt][ntl][rr] + pb;
                }
            }
    }
}

extern "C" void kernel_launch(void* const* d_in, const int* in_sizes, int n_in,
                              void* d_out, int out_size, void* d_ws, size_t ws_size,
                              hipStream_t stream) {
    const float* x   = (const float*)d_in[0];
    const float* Vw  = (const float*)d_in[1];
    const float* Vb  = (const float*)d_in[2];
    const float* QKw = (const float*)d_in[3];
    const float* QKb = (const float*)d_in[4];
    const float* Pw  = (const float*)d_in[5];
    const float* Pb  = (const float*)d_in[6];
    const float* Mw1 = (const float*)d_in[7];
    const float* Mb1 = (const float*)d_in[8];
    const float* Mw2 = (const float*)d_in[9];
    const float* Mb2 = (const float*)d_in[10];
    float* outp = (float*)d_out;

    unsigned short* wsb = (unsigned short*)d_ws;               // bf16 weights
    float* b2 = (float*)((char*)d_ws + WS_B2_OFF_B);           // bias2 table
    char* slabs = (char*)d_ws + WS_SLAB_OFF_B;                 // x-in / y-out slabs
    const int split = (ws_size >= (size_t)WS_TOTAL_B) ? 1 : 0;

    prep_kernel<<<dim3(672), dim3(256), 0, stream>>>(QKw, Vw, Pw, Mw1, Mb1, Mw2, Mb2, wsb, b2);
    if (split)
        xprep_kernel<<<dim3(512), dim3(256), 0, stream>>>(x, slabs);

    (void)hipFuncSetAttribute((const void*)fused_win_attn,
                              hipFuncAttributeMaxDynamicSharedMemorySize, LDS_BYTES);
    fused_win_attn<<<dim3(2048), dim3(512), LDS_BYTES, stream>>>(
        x, Vb, QKb, Pb, wsb, wsb + WS_WP_OFF_EL, b2, slabs, outp, split);

    if (split) {
        (void)hipFuncSetAttribute((const void*)proj_kernel,
                                  hipFuncAttributeMaxDynamicSharedMemorySize, 49152);
        proj_kernel<<<dim3(1024), dim3(256), 49152, stream>>>(
            slabs, wsb + WS_WP_OFF_EL, Pb, outp);
    }
}

// Round 14
// 286.995 us; speedup vs baseline: 1.3332x; 1.3332x over previous
//
#include <hip/hip_runtime.h>

// B=8, C=192, H=W=128, NH=6, HD=32, WS=8, N=64 tokens/window. 2048 windows.
// Round 14: round-13 structure, xprep rebuilt with LDS staging: block = 4
// wx-adjacent windows (512 thr, 96 KB LDS); coalesced x reads -> bf16 swizzled
// slab images in LDS -> contiguous full-line uint4 streams to d_ws. (Round 13's
// xprep used scattered 2B global stores: ~128 us. Predicted ~35 us.)
#define SCALEQ 0.17677669529663687f   // 32^-0.5

typedef __bf16 bf16x8 __attribute__((ext_vector_type(8)));
typedef __bf16 bf16x2 __attribute__((ext_vector_type(2)));
typedef float f32x4 __attribute__((ext_vector_type(4)));
typedef float f32x2 __attribute__((ext_vector_type(2)));

__device__ __forceinline__ float bflo(unsigned int u) { return __uint_as_float(u << 16); }
__device__ __forceinline__ float bfhi(unsigned int u) { return __uint_as_float(u & 0xffff0000u); }
__device__ __forceinline__ f32x2 b2x2(unsigned int u) {
    f32x2 r; r[0] = bflo(u); r[1] = bfhi(u); return r;
}
// native RNE converts (v_cvt_pk_bf16_f32)
__device__ __forceinline__ unsigned short f2b(float f) {
    return __builtin_bit_cast(unsigned short, (__bf16)f);
}
__device__ __forceinline__ unsigned int pk2(float a, float b) {
    bf16x2 v; v[0] = (__bf16)a; v[1] = (__bf16)b;
    return __builtin_bit_cast(unsigned int, v);
}

// LDS: 3 x 24 KB regions (swizzle byte ^= (row&7)<<4), time-multiplexed:
//  RA 0      xs[64][192] (P1-hoist) | q[64][192] (P2-P3) | v_n[64][192] (P3b-P4)
//  RB 24576  k[64][192]  (P2-P3)    | v_t[192][64] (P3b-P5)
//  RC 49152  o[64][192]  (P3-P4)    | y[64][192]  (P5-)
#define RA     0
#define RB     24576
#define RC     49152
#define LDS_BYTES 73728

// d_ws layout (bytes):
//  [0]      qkv weights bf16 [576][192] (q rows pre-scaled)   221184 B
//  [221184] proj weights bf16 [192][192]                       73728 B
//  [294912] bias2 f32 [6][64][64]                              98304 B
//  [393216] slab buffer [2048][24576 B]: xprep writes x-slabs; fused reads slab
//           wid at P1 then overwrites it with y at P5b; proj reads y slabs.
#define WS_WQKV_ELEMS 110592
#define WS_WP_OFF_EL  110592
#define WS_B2_OFF_B   294912
#define WS_SLAB_OFF_B 393216
#define WS_TOTAL_B    50724864

__device__ __forceinline__ bf16x8 ldsf(const char* p) {
    uint4 u = *(const uint4*)p;
    return __builtin_bit_cast(bf16x8, u);
}
__device__ __forceinline__ bf16x8 gldf(const unsigned short* p) {
    uint4 u = *(const uint4*)p;
    return __builtin_bit_cast(bf16x8, u);
}

// ---- prep kernel: weights f32->bf16 (q pre-scaled) + bias2 table. 672 blocks ----
__global__ void prep_kernel(const float* __restrict__ QKw, const float* __restrict__ Vw,
                            const float* __restrict__ Pw,
                            const float* __restrict__ Mw1, const float* __restrict__ Mb1,
                            const float* __restrict__ Mw2, const float* __restrict__ Mb2,
                            unsigned short* __restrict__ wsb, float* __restrict__ b2) {
    int gid = blockIdx.x * 256 + threadIdx.x;      // 0 .. 172031
    if (gid < WS_WQKV_ELEMS) {
        int r = gid / 192, c = gid - r * 192;
        float v = (r < 384) ? QKw[r * 192 + c] : Vw[(r - 384) * 192 + c];
        if (r < 192) v *= SCALEQ;
        wsb[gid] = f2b(v);
    } else if (gid < 147456) {
        int j = gid - WS_WQKV_ELEMS;
        wsb[WS_WP_OFF_EL + j] = f2b(Pw[j]);
    } else {
        int i = gid - 147456;                       // 0 .. 24575
        int h = i >> 12, n = (i >> 6) & 63, m = i & 63;
        float dy = (float)((n >> 3) - (m >> 3));
        float dx = (float)((n & 7) - (m & 7));
        float f0 = copysignf(log1pf(fabsf(dy)), dy);
        float f1 = copysignf(log1pf(fabsf(dx)), dx);
        float a = Mb2[h];
        for (int u = 0; u < 256; ++u) {
            float hv = fmaxf(f0 * Mw1[u] + f1 * Mw1[256 + u] + Mb1[u], 0.0f);
            a = fmaf(hv, Mw2[u * 6 + h], a);
        }
        b2[i] = a;
    }
}

// ---- xprep: x fp32 -> bf16 window slabs via LDS staging, full-line writes ----
// block = (b, wy, wxg): 4 wx-adjacent windows. 512 threads, 96 KB dynamic LDS.
__global__ __launch_bounds__(512)
void xprep_kernel(const float* __restrict__ x, char* __restrict__ xw) {
    extern __shared__ char lsm[];          // 4 slab images, 24576 B each
    const int t = threadIdx.x;
    const int blk = blockIdx.x;            // 0..511
    const int b = blk >> 6, wy = (blk >> 2) & 15, wxg = blk & 3;
    const float* xb = x + (size_t)b * 192 * 16384;

    // load: 12288 float4 / 512 thr = 24 iters; lanes 0..7 cover one row's 32 px
    #pragma unroll 4
    for (int i = 0; i < 24; ++i) {
        int idx = t + 512 * i;             // 0..12287
        int c = idx >> 6, rem = idx & 63;
        int r = rem >> 3, g = rem & 7;     // g = float4 group within 32 px
        float4 v4 = *(const float4*)(xb + c * 16384 + (wy * 8 + r) * 128 + wxg * 32 + g * 4);
        int s  = g >> 1;                   // slab (window) within block
        char* slab = lsm + s * 24576;
        int n0 = r * 8 + (g & 1) * 4;
        unsigned short sv[4] = {f2b(v4.x), f2b(v4.y), f2b(v4.z), f2b(v4.w)};
        #pragma unroll
        for (int e = 0; e < 4; ++e) {
            int n = n0 + e;
            *(unsigned short*)(slab + ((n * 384 + c * 2) ^ ((n & 7) << 4))) = sv[e];
        }
    }
    __syncthreads();

    // store: 4 slabs x 1536 uint4, contiguous full-line streams
    #pragma unroll
    for (int s = 0; s < 4; ++s) {
        int wid = (b << 8) | (wy << 4) | (wxg * 4 + s);
        char* dst = xw + (size_t)wid * 24576;
        const char* src = lsm + s * 24576;
        #pragma unroll
        for (int j = 0; j < 3; ++j) {
            int ch = t + 512 * j;          // 0..1535
            *(uint4*)(dst + ch * 16) = *(const uint4*)(src + ch * 16);
        }
    }
}

__global__ __launch_bounds__(512, 4)
void fused_win_attn(const float* __restrict__ x,
                    const float* __restrict__ Vb, const float* __restrict__ QKb,
                    const float* __restrict__ Pb,
                    const unsigned short* __restrict__ wqkv,   // bf16 [576][192]
                    const unsigned short* __restrict__ wp,     // bf16 [192][192]
                    const float* __restrict__ bias2,           // f32 [6][64][64]
                    char* __restrict__ slabs,                  // [2048][24576] x-in / y-out
                    float* __restrict__ out,
                    int split)
{
    extern __shared__ char smem[];
    const int t   = threadIdx.x;
    const int wv  = t >> 6;           // wave 0..7
    const int l15 = t & 15;
    const int l4  = (t >> 4) & 3;

    const int wid = ((blockIdx.x & 7) << 8) | (blockIdx.x >> 3);
    const int b   = wid >> 8;
    const int wy  = (wid >> 4) & 15;
    const int wx  = wid & 15;
    const int y0  = wy * 8, x0 = wx * 8;

    const f32x4 zz = {0.0f, 0.0f, 0.0f, 0.0f};

    // ---- P1: stage x slab -> RA ----
    if (split) {
        const char* slab = slabs + (size_t)wid * 24576;
        #pragma unroll
        for (int i = 0; i < 3; ++i) {
            int idx = t + 512 * i;               // 1536 uint4 chunks
            uint4 v = *(const uint4*)(slab + idx * 16);
            *(uint4*)(smem + RA + idx * 16) = v;
        }
    } else {
        const float* xb = x + (size_t)b * 192 * 16384;
        #pragma unroll
        for (int i = 0; i < 6; ++i) {
            int idx = t + 512 * i;
            int c = idx >> 4, sub = idx & 15;
            int r = sub >> 1, hf = sub & 1;
            float4 v4 = *(const float4*)(xb + c * 16384 + (y0 + r) * 128 + x0 + hf * 4);
            int n0 = r * 8 + hf * 4;
            unsigned short sv[4] = {f2b(v4.x), f2b(v4.y), f2b(v4.z), f2b(v4.w)};
            #pragma unroll
            for (int e = 0; e < 4; ++e) {
                int n = n0 + e;
                *(unsigned short*)(smem + RA + ((n * 384 + c * 2) ^ ((n & 7) << 4))) = sv[e];
            }
        }
    }
    __syncthreads();

    // ---- P2: qkv GEMM. wave (wcol, wrow): cols [48*wcol,+48) per tensor, toks [32*wrow,+32) ----
    const int wcol = wv & 3, wrow = wv >> 2;
    unsigned int vp[3][2][2];          // packed v held across conv: [j][mtl][tok-pair]
    {
        bf16x8 afr[6][2];
        #pragma unroll
        for (int ks = 0; ks < 6; ++ks)
            #pragma unroll
            for (int mtl = 0; mtl < 2; ++mtl) {
                int row = (wrow * 2 + mtl) * 16 + l15;
                afr[ks][mtl] = ldsf(smem + RA + ((row * 384 + ks * 64 + l4 * 16) ^ ((row & 7) << 4)));
            }
        __syncthreads();

        auto gemm3 = [&](int obase, f32x4 acc[3][2]) {
            bf16x8 bw[3][6];
            #pragma unroll
            for (int j = 0; j < 3; ++j) {
                const unsigned short* wr = wqkv + (size_t)(obase + j * 16 + l15) * 192 + l4 * 8;
                #pragma unroll
                for (int ks = 0; ks < 6; ++ks) bw[j][ks] = gldf(wr + ks * 32);
            }
            #pragma unroll
            for (int j = 0; j < 3; ++j) { acc[j][0] = zz; acc[j][1] = zz; }
            #pragma unroll
            for (int ks = 0; ks < 6; ++ks)
                #pragma unroll
                for (int j = 0; j < 3; ++j)
                    #pragma unroll
                    for (int mtl = 0; mtl < 2; ++mtl)
                        acc[j][mtl] = __builtin_amdgcn_mfma_f32_16x16x32_bf16(afr[ks][mtl], bw[j][ks], acc[j][mtl], 0, 0, 0);
        };

        // chunk 0: q -> region A (weights pre-scaled; bias scaled here)
        {
            f32x4 acc[3][2];
            gemm3(wcol * 48, acc);
            #pragma unroll
            for (int j = 0; j < 3; ++j) {
                int och = wcol * 48 + j * 16 + l15;
                float bv = QKb[och] * SCALEQ;
                #pragma unroll
                for (int mtl = 0; mtl < 2; ++mtl)
                    #pragma unroll
                    for (int rr = 0; rr < 4; ++rr) {
                        int tok = (wrow * 2 + mtl) * 16 + l4 * 4 + rr;
                        *(unsigned short*)(smem + RA + ((tok * 384 + och * 2) ^ ((tok & 7) << 4)))
                            = f2b(acc[j][mtl][rr] + bv);
                    }
            }
        }
        // chunk 1: k -> region B
        {
            f32x4 acc[3][2];
            gemm3(192 + wcol * 48, acc);
            #pragma unroll
            for (int j = 0; j < 3; ++j) {
                int ch = wcol * 48 + j * 16 + l15;
                float bv = QKb[192 + ch];
                #pragma unroll
                for (int mtl = 0; mtl < 2; ++mtl)
                    #pragma unroll
                    for (int rr = 0; rr < 4; ++rr) {
                        int tok = (wrow * 2 + mtl) * 16 + l4 * 4 + rr;
                        *(unsigned short*)(smem + RB + ((tok * 384 + ch * 2) ^ ((tok & 7) << 4)))
                            = f2b(acc[j][mtl][rr] + bv);
                    }
            }
        }
        // chunk 2: v -> registers (packed bf16 pairs along tok)
        {
            f32x4 acc[3][2];
            gemm3(384 + wcol * 48, acc);
            #pragma unroll
            for (int j = 0; j < 3; ++j) {
                int ch = wcol * 48 + j * 16 + l15;
                float bv = Vb[ch];
                #pragma unroll
                for (int mtl = 0; mtl < 2; ++mtl) {
                    vp[j][mtl][0] = pk2(acc[j][mtl][0] + bv, acc[j][mtl][1] + bv);
                    vp[j][mtl][1] = pk2(acc[j][mtl][2] + bv, acc[j][mtl][3] + bv);
                }
            }
        }
    }
    __syncthreads();

    // ---- P3: 8x8 circular conv q(A) x k(B) -> o(C). 384 threads, f32x2 packed ----
    if (t < 384) {
        const int rn = t / 48, cc = t % 48;
        const int c0b = cc * 8;               // byte offset of 4-ch chunk
        f32x2 acc[8][2];
        #pragma unroll
        for (int cn = 0; cn < 8; ++cn) {
            acc[cn][0] = (f32x2){0.0f, 0.0f};
            acc[cn][1] = (f32x2){0.0f, 0.0f};
        }
        #pragma unroll
        for (int kh = 0; kh < 2; ++kh) {
            uint2 karr[32];
            #pragma unroll
            for (int m = 0; m < 32; ++m) {
                int row = kh * 32 + m;
                karr[m] = *(const uint2*)(smem + RB + ((row * 384 + c0b) ^ ((row & 7) << 4)));
            }
            #pragma unroll
            for (int mrl = 0; mrl < 4; ++mrl) {
                const int mr = kh * 4 + mrl;
                f32x2 kf[8][2];
                #pragma unroll
                for (int mc = 0; mc < 8; ++mc) {
                    uint2 kv = karr[mrl * 8 + mc];
                    kf[mc][0] = b2x2(kv.x); kf[mc][1] = b2x2(kv.y);
                }
                const int npr = (rn - mr) & 7;
                #pragma unroll
                for (int npc = 0; npc < 8; ++npc) {
                    int np = npr * 8 + npc;
                    uint2 qv = *(const uint2*)(smem + RA + ((np * 384 + c0b) ^ ((np & 7) << 4)));
                    f32x2 qf0 = b2x2(qv.x), qf1 = b2x2(qv.y);
                    #pragma unroll
                    for (int mc = 0; mc < 8; ++mc) {
                        int cn = (npc + mc) & 7;
                        acc[cn][0] = qf0 * kf[mc][0] + acc[cn][0];
                        acc[cn][1] = qf1 * kf[mc][1] + acc[cn][1];
                    }
                }
            }
        }
        #pragma unroll
        for (int cn = 0; cn < 8; ++cn) {
            int n = rn * 8 + cn;
            uint2 pk;
            pk.x = pk2(acc[cn][0][0], acc[cn][0][1]);
            pk.y = pk2(acc[cn][1][0], acc[cn][1][1]);
            *(uint2*)(smem + RC + ((n * 384 + c0b) ^ ((n & 7) << 4))) = pk;
        }
    }
    __syncthreads();

    // ---- P3b: write held v regs -> v_n (A, over q) and v_t (B, over k) ----
    {
        #pragma unroll
        for (int j = 0; j < 3; ++j) {
            int ch = wcol * 48 + j * 16 + l15;
            #pragma unroll
            for (int mtl = 0; mtl < 2; ++mtl)
                #pragma unroll
                for (int pp = 0; pp < 2; ++pp) {
                    unsigned int pk = vp[j][mtl][pp];
                    int tok0 = (wrow * 2 + mtl) * 16 + l4 * 4 + pp * 2;
                    *(unsigned int*)(smem + RB + ((ch * 128 + tok0 * 2) ^ ((ch & 7) << 4))) = pk;
                    *(unsigned short*)(smem + RA + ((tok0 * 384 + ch * 2) ^ ((tok0 & 7) << 4)))
                        = (unsigned short)(pk & 0xffffu);
                    *(unsigned short*)(smem + RA + (((tok0 + 1) * 384 + ch * 2) ^ (((tok0 + 1) & 7) << 4)))
                        = (unsigned short)(pk >> 16);
                }
        }
    }
    __syncthreads();

    // ---- P4: S^T = mfma(v_n, o) + bias2, softmax over m, P packed in regs ----
    unsigned int pv[3][4][2];              // [unit][mt][pair]: P[n=l15-col][m]
    {
        #pragma unroll
        for (int i = 0; i < 3; ++i) {
            int u = wv * 3 + i;
            int h = u >> 2, nt = u & 3;
            int brow = nt * 16 + l15;
            bf16x8 ofr = ldsf(smem + RC + ((brow * 384 + h * 64 + l4 * 16) ^ ((brow & 7) << 4)));
            int n = nt * 16 + l15;
            const float* bp = bias2 + ((h * 64 + n) << 6) + l4 * 4;
            float s[4][4];
            #pragma unroll
            for (int mt = 0; mt < 4; ++mt) {
                int arow = mt * 16 + l15;
                bf16x8 vfr = ldsf(smem + RA + ((arow * 384 + h * 64 + l4 * 16) ^ ((arow & 7) << 4)));
                f32x4 a = __builtin_amdgcn_mfma_f32_16x16x32_bf16(vfr, ofr, zz, 0, 0, 0);
                float4 bb = *(const float4*)(bp + mt * 16);
                s[mt][0] = a[0] + bb.x; s[mt][1] = a[1] + bb.y;
                s[mt][2] = a[2] + bb.z; s[mt][3] = a[3] + bb.w;
            }
            float m0 = s[0][0];
            #pragma unroll
            for (int mt = 0; mt < 4; ++mt)
                #pragma unroll
                for (int rr = 0; rr < 4; ++rr) m0 = fmaxf(m0, s[mt][rr]);
            m0 = fmaxf(m0, __shfl_xor(m0, 16));
            m0 = fmaxf(m0, __shfl_xor(m0, 32));
            float sm = 0.0f;
            #pragma unroll
            for (int mt = 0; mt < 4; ++mt)
                #pragma unroll
                for (int rr = 0; rr < 4; ++rr) {
                    float p = __expf(s[mt][rr] - m0);
                    s[mt][rr] = p; sm += p;
                }
            sm += __shfl_xor(sm, 16);
            sm += __shfl_xor(sm, 32);
            float inv = 1.0f / sm;
            #pragma unroll
            for (int mt = 0; mt < 4; ++mt) {
                pv[i][mt][0] = pk2(s[mt][0] * inv, s[mt][1] * inv);
                pv[i][mt][1] = pk2(s[mt][2] * inv, s[mt][3] * inv);
            }
        }
    }
    __syncthreads();   // all units done reading o -> region C reusable

    // ---- P5: Y = mfma(P, v_t) -> y in RC ----
    {
        #pragma unroll
        for (int i = 0; i < 3; ++i) {
            int u = wv * 3 + i;
            int h = u >> 2, nt = u & 3;
            bf16x8 pafr[2];
            #pragma unroll
            for (int ks = 0; ks < 2; ++ks) {
                unsigned int au[4];
                #pragma unroll
                for (int p = 0; p < 4; ++p) {
                    int srcl4 = (2 * l4 + (p >> 1)) & 3;
                    int src = srcl4 * 16 + l15;
                    unsigned int v0 = (unsigned int)__shfl((int)pv[i][2 * ks][p & 1], src, 64);
                    unsigned int v1 = (unsigned int)__shfl((int)pv[i][2 * ks + 1][p & 1], src, 64);
                    au[p] = (l4 & 2) ? v1 : v0;
                }
                uint4 u4 = {au[0], au[1], au[2], au[3]};
                pafr[ks] = __builtin_bit_cast(bf16x8, u4);
            }
            f32x4 acc[2];
            acc[0] = zz; acc[1] = zz;
            #pragma unroll
            for (int dt = 0; dt < 2; ++dt)
                #pragma unroll
                for (int ks = 0; ks < 2; ++ks) {
                    int drow = h * 32 + dt * 16 + l15;
                    bf16x8 vtf = ldsf(smem + RB + ((drow * 128 + ks * 64 + l4 * 16) ^ ((drow & 7) << 4)));
                    acc[dt] = __builtin_amdgcn_mfma_f32_16x16x32_bf16(pafr[ks], vtf, acc[dt], 0, 0, 0);
                }
            #pragma unroll
            for (int dt = 0; dt < 2; ++dt)
                #pragma unroll
                for (int rr = 0; rr < 4; ++rr) {
                    int tok = nt * 16 + l4 * 4 + rr;
                    int ch  = h * 32 + dt * 16 + l15;
                    *(unsigned short*)(smem + RC + ((tok * 384 + ch * 2) ^ ((tok & 7) << 4))) = f2b(acc[dt][rr]);
                }
        }
    }
    __syncthreads();

    if (split) {
        // ---- P5b: raw copy RC (24 KB, swizzled) -> slab wid (over x image) ----
        char* ybw = slabs + (size_t)wid * 24576;
        #pragma unroll
        for (int c = 0; c < 3; ++c) {
            int idx = t + 512 * c;               // 0..1535 uint4 chunks
            uint4 v = *(const uint4*)(smem + RC + idx * 16);
            *(uint4*)(ybw + idx * 16) = v;
        }
        return;
    }

    // ---- P6 (fallback only): proj OUT^T[oc][tok] = Pw . y^T ----
    {
        const int wc = wv & 3, wr = wv >> 2;
        bf16x8 wfr[3][6];
        #pragma unroll
        for (int jt = 0; jt < 3; ++jt) {
            int oc = wc * 48 + jt * 16;
            const unsigned short* wr_ = wp + (size_t)(oc + l15) * 192 + l4 * 8;
            #pragma unroll
            for (int ks = 0; ks < 6; ++ks) wfr[jt][ks] = gldf(wr_ + ks * 32);
        }
        f32x4 acc[3][2];
        #pragma unroll
        for (int jt = 0; jt < 3; ++jt) { acc[jt][0] = zz; acc[jt][1] = zz; }

        #pragma unroll
        for (int ks = 0; ks < 6; ++ks) {
            bf16x8 bfr[2];
            #pragma unroll
            for (int ntl = 0; ntl < 2; ++ntl) {
                int tok = (wr * 2 + ntl) * 16 + l15;
                bfr[ntl] = ldsf(smem + RC + ((tok * 384 + ks * 64 + l4 * 16) ^ ((tok & 7) << 4)));
            }
            #pragma unroll
            for (int jt = 0; jt < 3; ++jt)
                #pragma unroll
                for (int ntl = 0; ntl < 2; ++ntl)
                    acc[jt][ntl] = __builtin_amdgcn_mfma_f32_16x16x32_bf16(wfr[jt][ks], bfr[ntl], acc[jt][ntl], 0, 0, 0);
        }
        #pragma unroll
        for (int jt = 0; jt < 3; ++jt)
            #pragma unroll
            for (int rr = 0; rr < 4; ++rr) {
                int oc = wc * 48 + jt * 16 + l4 * 4 + rr;
                float pb = Pb[oc];
                float* obase = out + (size_t)(b * 192 + oc) * 16384;
                #pragma unroll
                for (int ntl = 0; ntl < 2; ++ntl) {
                    int tok = (wr * 2 + ntl) * 16 + l15;
                    obase[(y0 + (tok >> 3)) * 128 + x0 + (tok & 7)] = acc[jt][ntl][rr] + pb;
                }
            }
    }
}

// ---- proj kernel (split mode): one output row y per block, full-line writes ----
__global__ __launch_bounds__(256)
void proj_kernel(const char* __restrict__ yb,             // raw [2048][24576]
                 const unsigned short* __restrict__ wp,   // bf16 [192][192]
                 const float* __restrict__ Pb,
                 float* __restrict__ out)
{
    extern __shared__ char smem[];                        // ya[128 px][192 ch] bf16 swizzled
    const int t   = threadIdx.x;
    const int wv  = t >> 6;          // wave 0..3
    const int l15 = t & 15;
    const int l4  = (t >> 4) & 3;

    const int by = blockIdx.x;       // 0..1023
    const int b  = by >> 7;
    const int y  = by & 127;
    const int wy = y >> 3, row = y & 7;

    const f32x4 zz = {0.0f, 0.0f, 0.0f, 0.0f};

    // stage raw swizzled slabs: window wx's toks row*8..row*8+7 = contiguous 3072 B.
    #pragma unroll
    for (int k = 0; k < 12; ++k) {
        int i = t + 256 * k;         // 0..3071 = (px, 16B-chunk cb)
        int px = i / 24, cb = i % 24;
        int wx = px >> 3, col = px & 7;
        const char* src = yb + (size_t)(((b * 16 + wy) * 16 + wx)) * 24576
                        + row * 3072 + col * 384 + cb * 16;
        uint4 v = *(const uint4*)src;
        *(uint4*)(smem + px * 384 + cb * 16) = v;
    }
    __syncthreads();

    bf16x8 wfr[3][6];
    #pragma unroll
    for (int jt = 0; jt < 3; ++jt) {
        int oc = wv * 48 + jt * 16;
        const unsigned short* wr_ = wp + (size_t)(oc + l15) * 192 + l4 * 8;
        #pragma unroll
        for (int ks = 0; ks < 6; ++ks) wfr[jt][ks] = gldf(wr_ + ks * 32);
    }
    #pragma unroll
    for (int half = 0; half < 2; ++half) {
        f32x4 acc[3][4];
        #pragma unroll
        for (int jt = 0; jt < 3; ++jt)
            #pragma unroll
            for (int ntl = 0; ntl < 4; ++ntl) acc[jt][ntl] = zz;
        #pragma unroll
        for (int ks = 0; ks < 6; ++ks) {
            bf16x8 bfr[4];
            #pragma unroll
            for (int ntl = 0; ntl < 4; ++ntl) {
                int px = (half * 4 + ntl) * 16 + l15;
                bfr[ntl] = ldsf(smem + ((px * 384 + ks * 64 + l4 * 16) ^ ((px & 7) << 4)));
            }
            #pragma unroll
            for (int jt = 0; jt < 3; ++jt)
                #pragma unroll
                for (int ntl = 0; ntl < 4; ++ntl)
                    acc[jt][ntl] = __builtin_amdgcn_mfma_f32_16x16x32_bf16(wfr[jt][ks], bfr[ntl], acc[jt][ntl], 0, 0, 0);
        }
        #pragma unroll
        for (int jt = 0; jt < 3; ++jt)
            #pragma unroll
            for (int rr = 0; rr < 4; ++rr) {
                int oc = wv * 48 + jt * 16 + l4 * 4 + rr;
                float pb = Pb[oc];
                float* op = out + ((size_t)(b * 192 + oc) * 128 + y) * 128;
                #pragma unroll
                for (int ntl = 0; ntl < 4; ++ntl) {
                    int px = (half * 4 + ntl) * 16 + l15;
                    op[px] = acc[jt][ntl][rr] + pb;
                }
            }
    }
}

extern "C" void kernel_launch(void* const* d_in, const int* in_sizes, int n_in,
                              void* d_out, int out_size, void* d_ws, size_t ws_size,
                              hipStream_t stream) {
    const float* x   = (const float*)d_in[0];
    const float* Vw  = (const float*)d_in[1];
    const float* Vb  = (const float*)d_in[2];
    const float* QKw = (const float*)d_in[3];
    const float* QKb = (const float*)d_in[4];
    const float* Pw  = (const float*)d_in[5];
    const float* Pb  = (const float*)d_in[6];
    const float* Mw1 = (const float*)d_in[7];
    const float* Mb1 = (const float*)d_in[8];
    const float* Mw2 = (const float*)d_in[9];
    const float* Mb2 = (const float*)d_in[10];
    float* outp = (float*)d_out;

    unsigned short* wsb = (unsigned short*)d_ws;               // bf16 weights
    float* b2 = (float*)((char*)d_ws + WS_B2_OFF_B);           // bias2 table
    char* slabs = (char*)d_ws + WS_SLAB_OFF_B;                 // x-in / y-out slabs
    const int split = (ws_size >= (size_t)WS_TOTAL_B) ? 1 : 0;

    prep_kernel<<<dim3(672), dim3(256), 0, stream>>>(QKw, Vw, Pw, Mw1, Mb1, Mw2, Mb2, wsb, b2);
    if (split) {
        (void)hipFuncSetAttribute((const void*)xprep_kernel,
                                  hipFuncAttributeMaxDynamicSharedMemorySize, 98304);
        xprep_kernel<<<dim3(512), dim3(512), 98304, stream>>>(x, slabs);
    }

    (void)hipFuncSetAttribute((const void*)fused_win_attn,
                              hipFuncAttributeMaxDynamicSharedMemorySize, LDS_BYTES);
    fused_win_attn<<<dim3(2048), dim3(512), LDS_BYTES, stream>>>(
        x, Vb, QKb, Pb, wsb, wsb + WS_WP_OFF_EL, b2, slabs, outp, split);

    if (split) {
        (void)hipFuncSetAttribute((const void*)proj_kernel,
                                  hipFuncAttributeMaxDynamicSharedMemorySize, 49152);
        proj_kernel<<<dim3(1024), dim3(256), 49152, stream>>>(
            slabs, wsb + WS_WP_OFF_EL, Pb, outp);
    }
}

// Round 16
// 282.895 us; speedup vs baseline: 1.3525x; 1.0145x over previous
//
#include <hip/hip_runtime.h>

// B=8, C=192, H=W=128, NH=6, HD=32, WS=8, N=64 tokens/window. 2048 windows.
// Round 16: round-15 (NT slab I/O) with the compile fix: nontemporal builtins
// take clang ext_vector u32x4, not HIP_vector_type uint4.
#define SCALEQ 0.17677669529663687f   // 32^-0.5

typedef __bf16 bf16x8 __attribute__((ext_vector_type(8)));
typedef __bf16 bf16x2 __attribute__((ext_vector_type(2)));
typedef float f32x4 __attribute__((ext_vector_type(4)));
typedef float f32x2 __attribute__((ext_vector_type(2)));
typedef unsigned int u32x4 __attribute__((ext_vector_type(4)));   // NT-compatible 16B

__device__ __forceinline__ float bflo(unsigned int u) { return __uint_as_float(u << 16); }
__device__ __forceinline__ float bfhi(unsigned int u) { return __uint_as_float(u & 0xffff0000u); }
__device__ __forceinline__ f32x2 b2x2(unsigned int u) {
    f32x2 r; r[0] = bflo(u); r[1] = bfhi(u); return r;
}
// native RNE converts (v_cvt_pk_bf16_f32)
__device__ __forceinline__ unsigned short f2b(float f) {
    return __builtin_bit_cast(unsigned short, (__bf16)f);
}
__device__ __forceinline__ unsigned int pk2(float a, float b) {
    bf16x2 v; v[0] = (__bf16)a; v[1] = (__bf16)b;
    return __builtin_bit_cast(unsigned int, v);
}

// LDS: 3 x 24 KB regions (swizzle byte ^= (row&7)<<4), time-multiplexed:
//  RA 0      xs[64][192] (P1-hoist) | q[64][192] (P2-P3) | v_n[64][192] (P3b-P4)
//  RB 24576  k[64][192]  (P2-P3)    | v_t[192][64] (P3b-P5)
//  RC 49152  o[64][192]  (P3-P4)    | y[64][192]  (P5-)
#define RA     0
#define RB     24576
#define RC     49152
#define LDS_BYTES 73728

// d_ws layout (bytes):
//  [0]      qkv weights bf16 [576][192] (q rows pre-scaled)   221184 B
//  [221184] proj weights bf16 [192][192]                       73728 B
//  [294912] bias2 f32 [6][64][64]                              98304 B
//  [393216] slab buffer [2048][24576 B]: xprep writes x-slabs; fused reads slab
//           wid at P1 then overwrites it with y at P5b; proj reads y slabs.
#define WS_WQKV_ELEMS 110592
#define WS_WP_OFF_EL  110592
#define WS_B2_OFF_B   294912
#define WS_SLAB_OFF_B 393216
#define WS_TOTAL_B    50724864

__device__ __forceinline__ bf16x8 ldsf(const char* p) {
    u32x4 u = *(const u32x4*)p;
    return __builtin_bit_cast(bf16x8, u);
}
__device__ __forceinline__ bf16x8 gldf(const unsigned short* p) {
    u32x4 u = *(const u32x4*)p;
    return __builtin_bit_cast(bf16x8, u);
}

// ---- prep kernel: weights f32->bf16 (q pre-scaled) + bias2 table. 672 blocks ----
__global__ void prep_kernel(const float* __restrict__ QKw, const float* __restrict__ Vw,
                            const float* __restrict__ Pw,
                            const float* __restrict__ Mw1, const float* __restrict__ Mb1,
                            const float* __restrict__ Mw2, const float* __restrict__ Mb2,
                            unsigned short* __restrict__ wsb, float* __restrict__ b2) {
    int gid = blockIdx.x * 256 + threadIdx.x;      // 0 .. 172031
    if (gid < WS_WQKV_ELEMS) {
        int r = gid / 192, c = gid - r * 192;
        float v = (r < 384) ? QKw[r * 192 + c] : Vw[(r - 384) * 192 + c];
        if (r < 192) v *= SCALEQ;
        wsb[gid] = f2b(v);
    } else if (gid < 147456) {
        int j = gid - WS_WQKV_ELEMS;
        wsb[WS_WP_OFF_EL + j] = f2b(Pw[j]);
    } else {
        int i = gid - 147456;                       // 0 .. 24575
        int h = i >> 12, n = (i >> 6) & 63, m = i & 63;
        float dy = (float)((n >> 3) - (m >> 3));
        float dx = (float)((n & 7) - (m & 7));
        float f0 = copysignf(log1pf(fabsf(dy)), dy);
        float f1 = copysignf(log1pf(fabsf(dx)), dx);
        float a = Mb2[h];
        for (int u = 0; u < 256; ++u) {
            float hv = fmaxf(f0 * Mw1[u] + f1 * Mw1[256 + u] + Mb1[u], 0.0f);
            a = fmaf(hv, Mw2[u * 6 + h], a);
        }
        b2[i] = a;
    }
}

// ---- xprep: x fp32 -> bf16 window slabs via LDS staging, NT full-line writes ----
// block = (b, wy, wxg): 4 wx-adjacent windows. 512 threads, 96 KB dynamic LDS.
__global__ __launch_bounds__(512)
void xprep_kernel(const float* __restrict__ x, char* __restrict__ xw) {
    extern __shared__ char lsm[];          // 4 slab images, 24576 B each
    const int t = threadIdx.x;
    const int blk = blockIdx.x;            // 0..511
    const int b = blk >> 6, wy = (blk >> 2) & 15, wxg = blk & 3;
    const float* xb = x + (size_t)b * 192 * 16384;

    // load: 12288 float4 / 512 thr = 24 iters; lanes 0..7 cover one row's 32 px
    #pragma unroll 4
    for (int i = 0; i < 24; ++i) {
        int idx = t + 512 * i;             // 0..12287
        int c = idx >> 6, rem = idx & 63;
        int r = rem >> 3, g = rem & 7;     // g = float4 group within 32 px
        float4 v4 = *(const float4*)(xb + c * 16384 + (wy * 8 + r) * 128 + wxg * 32 + g * 4);
        int s  = g >> 1;                   // slab (window) within block
        char* slab = lsm + s * 24576;
        int n0 = r * 8 + (g & 1) * 4;
        unsigned short sv[4] = {f2b(v4.x), f2b(v4.y), f2b(v4.z), f2b(v4.w)};
        #pragma unroll
        for (int e = 0; e < 4; ++e) {
            int n = n0 + e;
            *(unsigned short*)(slab + ((n * 384 + c * 2) ^ ((n & 7) << 4))) = sv[e];
        }
    }
    __syncthreads();

    // store: 4 slabs x 1536 u32x4, contiguous full-line NT streams
    #pragma unroll
    for (int s = 0; s < 4; ++s) {
        int wid = (b << 8) | (wy << 4) | (wxg * 4 + s);
        char* dst = xw + (size_t)wid * 24576;
        const char* src = lsm + s * 24576;
        #pragma unroll
        for (int j = 0; j < 3; ++j) {
            int ch = t + 512 * j;          // 0..1535
            u32x4 v = *(const u32x4*)(src + ch * 16);
            __builtin_nontemporal_store(v, (u32x4*)(dst + ch * 16));
        }
    }
}

__global__ __launch_bounds__(512, 4)
void fused_win_attn(const float* __restrict__ x,
                    const float* __restrict__ Vb, const float* __restrict__ QKb,
                    const float* __restrict__ Pb,
                    const unsigned short* __restrict__ wqkv,   // bf16 [576][192]
                    const unsigned short* __restrict__ wp,     // bf16 [192][192]
                    const float* __restrict__ bias2,           // f32 [6][64][64]
                    char* __restrict__ slabs,                  // [2048][24576] x-in / y-out
                    float* __restrict__ out,
                    int split)
{
    extern __shared__ char smem[];
    const int t   = threadIdx.x;
    const int wv  = t >> 6;           // wave 0..7
    const int l15 = t & 15;
    const int l4  = (t >> 4) & 3;

    const int wid = ((blockIdx.x & 7) << 8) | (blockIdx.x >> 3);
    const int b   = wid >> 8;
    const int wy  = (wid >> 4) & 15;
    const int wx  = wid & 15;
    const int y0  = wy * 8, x0 = wx * 8;

    const f32x4 zz = {0.0f, 0.0f, 0.0f, 0.0f};

    // ---- P1: stage x slab -> RA (NT loads: single-use stream) ----
    if (split) {
        const char* slab = slabs + (size_t)wid * 24576;
        #pragma unroll
        for (int i = 0; i < 3; ++i) {
            int idx = t + 512 * i;               // 1536 u32x4 chunks
            u32x4 v = __builtin_nontemporal_load((const u32x4*)(slab + idx * 16));
            *(u32x4*)(smem + RA + idx * 16) = v;
        }
    } else {
        const float* xb = x + (size_t)b * 192 * 16384;
        #pragma unroll
        for (int i = 0; i < 6; ++i) {
            int idx = t + 512 * i;
            int c = idx >> 4, sub = idx & 15;
            int r = sub >> 1, hf = sub & 1;
            float4 v4 = *(const float4*)(xb + c * 16384 + (y0 + r) * 128 + x0 + hf * 4);
            int n0 = r * 8 + hf * 4;
            unsigned short sv[4] = {f2b(v4.x), f2b(v4.y), f2b(v4.z), f2b(v4.w)};
            #pragma unroll
            for (int e = 0; e < 4; ++e) {
                int n = n0 + e;
                *(unsigned short*)(smem + RA + ((n * 384 + c * 2) ^ ((n & 7) << 4))) = sv[e];
            }
        }
    }
    __syncthreads();

    // ---- P2: qkv GEMM. wave (wcol, wrow): cols [48*wcol,+48) per tensor, toks [32*wrow,+32) ----
    const int wcol = wv & 3, wrow = wv >> 2;
    unsigned int vp[3][2][2];          // packed v held across conv: [j][mtl][tok-pair]
    {
        bf16x8 afr[6][2];
        #pragma unroll
        for (int ks = 0; ks < 6; ++ks)
            #pragma unroll
            for (int mtl = 0; mtl < 2; ++mtl) {
                int row = (wrow * 2 + mtl) * 16 + l15;
                afr[ks][mtl] = ldsf(smem + RA + ((row * 384 + ks * 64 + l4 * 16) ^ ((row & 7) << 4)));
            }
        __syncthreads();

        auto gemm3 = [&](int obase, f32x4 acc[3][2]) {
            bf16x8 bw[3][6];
            #pragma unroll
            for (int j = 0; j < 3; ++j) {
                const unsigned short* wr = wqkv + (size_t)(obase + j * 16 + l15) * 192 + l4 * 8;
                #pragma unroll
                for (int ks = 0; ks < 6; ++ks) bw[j][ks] = gldf(wr + ks * 32);
            }
            #pragma unroll
            for (int j = 0; j < 3; ++j) { acc[j][0] = zz; acc[j][1] = zz; }
            #pragma unroll
            for (int ks = 0; ks < 6; ++ks)
                #pragma unroll
                for (int j = 0; j < 3; ++j)
                    #pragma unroll
                    for (int mtl = 0; mtl < 2; ++mtl)
                        acc[j][mtl] = __builtin_amdgcn_mfma_f32_16x16x32_bf16(afr[ks][mtl], bw[j][ks], acc[j][mtl], 0, 0, 0);
        };

        // chunk 0: q -> region A (weights pre-scaled; bias scaled here)
        {
            f32x4 acc[3][2];
            gemm3(wcol * 48, acc);
            #pragma unroll
            for (int j = 0; j < 3; ++j) {
                int och = wcol * 48 + j * 16 + l15;
                float bv = QKb[och] * SCALEQ;
                #pragma unroll
                for (int mtl = 0; mtl < 2; ++mtl)
                    #pragma unroll
                    for (int rr = 0; rr < 4; ++rr) {
                        int tok = (wrow * 2 + mtl) * 16 + l4 * 4 + rr;
                        *(unsigned short*)(smem + RA + ((tok * 384 + och * 2) ^ ((tok & 7) << 4)))
                            = f2b(acc[j][mtl][rr] + bv);
                    }
            }
        }
        // chunk 1: k -> region B
        {
            f32x4 acc[3][2];
            gemm3(192 + wcol * 48, acc);
            #pragma unroll
            for (int j = 0; j < 3; ++j) {
                int ch = wcol * 48 + j * 16 + l15;
                float bv = QKb[192 + ch];
                #pragma unroll
                for (int mtl = 0; mtl < 2; ++mtl)
                    #pragma unroll
                    for (int rr = 0; rr < 4; ++rr) {
                        int tok = (wrow * 2 + mtl) * 16 + l4 * 4 + rr;
                        *(unsigned short*)(smem + RB + ((tok * 384 + ch * 2) ^ ((tok & 7) << 4)))
                            = f2b(acc[j][mtl][rr] + bv);
                    }
            }
        }
        // chunk 2: v -> registers (packed bf16 pairs along tok)
        {
            f32x4 acc[3][2];
            gemm3(384 + wcol * 48, acc);
            #pragma unroll
            for (int j = 0; j < 3; ++j) {
                int ch = wcol * 48 + j * 16 + l15;
                float bv = Vb[ch];
                #pragma unroll
                for (int mtl = 0; mtl < 2; ++mtl) {
                    vp[j][mtl][0] = pk2(acc[j][mtl][0] + bv, acc[j][mtl][1] + bv);
                    vp[j][mtl][1] = pk2(acc[j][mtl][2] + bv, acc[j][mtl][3] + bv);
                }
            }
        }
    }
    __syncthreads();

    // ---- P3: 8x8 circular conv q(A) x k(B) -> o(C). 384 threads, f32x2 packed ----
    if (t < 384) {
        const int rn = t / 48, cc = t % 48;
        const int c0b = cc * 8;               // byte offset of 4-ch chunk
        f32x2 acc[8][2];
        #pragma unroll
        for (int cn = 0; cn < 8; ++cn) {
            acc[cn][0] = (f32x2){0.0f, 0.0f};
            acc[cn][1] = (f32x2){0.0f, 0.0f};
        }
        #pragma unroll
        for (int kh = 0; kh < 2; ++kh) {
            uint2 karr[32];
            #pragma unroll
            for (int m = 0; m < 32; ++m) {
                int row = kh * 32 + m;
                karr[m] = *(const uint2*)(smem + RB + ((row * 384 + c0b) ^ ((row & 7) << 4)));
            }
            #pragma unroll
            for (int mrl = 0; mrl < 4; ++mrl) {
                const int mr = kh * 4 + mrl;
                f32x2 kf[8][2];
                #pragma unroll
                for (int mc = 0; mc < 8; ++mc) {
                    uint2 kv = karr[mrl * 8 + mc];
                    kf[mc][0] = b2x2(kv.x); kf[mc][1] = b2x2(kv.y);
                }
                const int npr = (rn - mr) & 7;
                #pragma unroll
                for (int npc = 0; npc < 8; ++npc) {
                    int np = npr * 8 + npc;
                    uint2 qv = *(const uint2*)(smem + RA + ((np * 384 + c0b) ^ ((np & 7) << 4)));
                    f32x2 qf0 = b2x2(qv.x), qf1 = b2x2(qv.y);
                    #pragma unroll
                    for (int mc = 0; mc < 8; ++mc) {
                        int cn = (npc + mc) & 7;
                        acc[cn][0] = qf0 * kf[mc][0] + acc[cn][0];
                        acc[cn][1] = qf1 * kf[mc][1] + acc[cn][1];
                    }
                }
            }
        }
        #pragma unroll
        for (int cn = 0; cn < 8; ++cn) {
            int n = rn * 8 + cn;
            uint2 pk;
            pk.x = pk2(acc[cn][0][0], acc[cn][0][1]);
            pk.y = pk2(acc[cn][1][0], acc[cn][1][1]);
            *(uint2*)(smem + RC + ((n * 384 + c0b) ^ ((n & 7) << 4))) = pk;
        }
    }
    __syncthreads();

    // ---- P3b: write held v regs -> v_n (A, over q) and v_t (B, over k) ----
    {
        #pragma unroll
        for (int j = 0; j < 3; ++j) {
            int ch = wcol * 48 + j * 16 + l15;
            #pragma unroll
            for (int mtl = 0; mtl < 2; ++mtl)
                #pragma unroll
                for (int pp = 0; pp < 2; ++pp) {
                    unsigned int pk = vp[j][mtl][pp];
                    int tok0 = (wrow * 2 + mtl) * 16 + l4 * 4 + pp * 2;
                    *(unsigned int*)(smem + RB + ((ch * 128 + tok0 * 2) ^ ((ch & 7) << 4))) = pk;
                    *(unsigned short*)(smem + RA + ((tok0 * 384 + ch * 2) ^ ((tok0 & 7) << 4)))
                        = (unsigned short)(pk & 0xffffu);
                    *(unsigned short*)(smem + RA + (((tok0 + 1) * 384 + ch * 2) ^ (((tok0 + 1) & 7) << 4)))
                        = (unsigned short)(pk >> 16);
                }
        }
    }
    __syncthreads();

    // ---- P4: S^T = mfma(v_n, o) + bias2, softmax over m, P packed in regs ----
    unsigned int pv[3][4][2];              // [unit][mt][pair]: P[n=l15-col][m]
    {
        #pragma unroll
        for (int i = 0; i < 3; ++i) {
            int u = wv * 3 + i;
            int h = u >> 2, nt = u & 3;
            int brow = nt * 16 + l15;
            bf16x8 ofr = ldsf(smem + RC + ((brow * 384 + h * 64 + l4 * 16) ^ ((brow & 7) << 4)));
            int n = nt * 16 + l15;
            const float* bp = bias2 + ((h * 64 + n) << 6) + l4 * 4;
            float s[4][4];
            #pragma unroll
            for (int mt = 0; mt < 4; ++mt) {
                int arow = mt * 16 + l15;
                bf16x8 vfr = ldsf(smem + RA + ((arow * 384 + h * 64 + l4 * 16) ^ ((arow & 7) << 4)));
                f32x4 a = __builtin_amdgcn_mfma_f32_16x16x32_bf16(vfr, ofr, zz, 0, 0, 0);
                float4 bb = *(const float4*)(bp + mt * 16);
                s[mt][0] = a[0] + bb.x; s[mt][1] = a[1] + bb.y;
                s[mt][2] = a[2] + bb.z; s[mt][3] = a[3] + bb.w;
            }
            float m0 = s[0][0];
            #pragma unroll
            for (int mt = 0; mt < 4; ++mt)
                #pragma unroll
                for (int rr = 0; rr < 4; ++rr) m0 = fmaxf(m0, s[mt][rr]);
            m0 = fmaxf(m0, __shfl_xor(m0, 16));
            m0 = fmaxf(m0, __shfl_xor(m0, 32));
            float sm = 0.0f;
            #pragma unroll
            for (int mt = 0; mt < 4; ++mt)
                #pragma unroll
                for (int rr = 0; rr < 4; ++rr) {
                    float p = __expf(s[mt][rr] - m0);
                    s[mt][rr] = p; sm += p;
                }
            sm += __shfl_xor(sm, 16);
            sm += __shfl_xor(sm, 32);
            float inv = 1.0f / sm;
            #pragma unroll
            for (int mt = 0; mt < 4; ++mt) {
                pv[i][mt][0] = pk2(s[mt][0] * inv, s[mt][1] * inv);
                pv[i][mt][1] = pk2(s[mt][2] * inv, s[mt][3] * inv);
            }
        }
    }
    __syncthreads();   // all units done reading o -> region C reusable

    // ---- P5: Y = mfma(P, v_t) -> y in RC ----
    {
        #pragma unroll
        for (int i = 0; i < 3; ++i) {
            int u = wv * 3 + i;
            int h = u >> 2, nt = u & 3;
            bf16x8 pafr[2];
            #pragma unroll
            for (int ks = 0; ks < 2; ++ks) {
                unsigned int au[4];
                #pragma unroll
                for (int p = 0; p < 4; ++p) {
                    int srcl4 = (2 * l4 + (p >> 1)) & 3;
                    int src = srcl4 * 16 + l15;
                    unsigned int v0 = (unsigned int)__shfl((int)pv[i][2 * ks][p & 1], src, 64);
                    unsigned int v1 = (unsigned int)__shfl((int)pv[i][2 * ks + 1][p & 1], src, 64);
                    au[p] = (l4 & 2) ? v1 : v0;
                }
                u32x4 u4 = {au[0], au[1], au[2], au[3]};
                pafr[ks] = __builtin_bit_cast(bf16x8, u4);
            }
            f32x4 acc[2];
            acc[0] = zz; acc[1] = zz;
            #pragma unroll
            for (int dt = 0; dt < 2; ++dt)
                #pragma unroll
                for (int ks = 0; ks < 2; ++ks) {
                    int drow = h * 32 + dt * 16 + l15;
                    bf16x8 vtf = ldsf(smem + RB + ((drow * 128 + ks * 64 + l4 * 16) ^ ((drow & 7) << 4)));
                    acc[dt] = __builtin_amdgcn_mfma_f32_16x16x32_bf16(pafr[ks], vtf, acc[dt], 0, 0, 0);
                }
            #pragma unroll
            for (int dt = 0; dt < 2; ++dt)
                #pragma unroll
                for (int rr = 0; rr < 4; ++rr) {
                    int tok = nt * 16 + l4 * 4 + rr;
                    int ch  = h * 32 + dt * 16 + l15;
                    *(unsigned short*)(smem + RC + ((tok * 384 + ch * 2) ^ ((tok & 7) << 4))) = f2b(acc[dt][rr]);
                }
        }
    }
    __syncthreads();

    if (split) {
        // ---- P5b: raw copy RC (24 KB, swizzled) -> slab wid, NT full-line ----
        char* ybw = slabs + (size_t)wid * 24576;
        #pragma unroll
        for (int c = 0; c < 3; ++c) {
            int idx = t + 512 * c;               // 0..1535 u32x4 chunks
            u32x4 v = *(const u32x4*)(smem + RC + idx * 16);
            __builtin_nontemporal_store(v, (u32x4*)(ybw + idx * 16));
        }
        return;
    }

    // ---- P6 (fallback only): proj OUT^T[oc][tok] = Pw . y^T ----
    {
        const int wc = wv & 3, wr = wv >> 2;
        bf16x8 wfr[3][6];
        #pragma unroll
        for (int jt = 0; jt < 3; ++jt) {
            int oc = wc * 48 + jt * 16;
            const unsigned short* wr_ = wp + (size_t)(oc + l15) * 192 + l4 * 8;
            #pragma unroll
            for (int ks = 0; ks < 6; ++ks) wfr[jt][ks] = gldf(wr_ + ks * 32);
        }
        f32x4 acc[3][2];
        #pragma unroll
        for (int jt = 0; jt < 3; ++jt) { acc[jt][0] = zz; acc[jt][1] = zz; }

        #pragma unroll
        for (int ks = 0; ks < 6; ++ks) {
            bf16x8 bfr[2];
            #pragma unroll
            for (int ntl = 0; ntl < 2; ++ntl) {
                int tok = (wr * 2 + ntl) * 16 + l15;
                bfr[ntl] = ldsf(smem + RC + ((tok * 384 + ks * 64 + l4 * 16) ^ ((tok & 7) << 4)));
            }
            #pragma unroll
            for (int jt = 0; jt < 3; ++jt)
                #pragma unroll
                for (int ntl = 0; ntl < 2; ++ntl)
                    acc[jt][ntl] = __builtin_amdgcn_mfma_f32_16x16x32_bf16(wfr[jt][ks], bfr[ntl], acc[jt][ntl], 0, 0, 0);
        }
        #pragma unroll
        for (int jt = 0; jt < 3; ++jt)
            #pragma unroll
            for (int rr = 0; rr < 4; ++rr) {
                int oc = wc * 48 + jt * 16 + l4 * 4 + rr;
                float pb = Pb[oc];
                float* obase = out + (size_t)(b * 192 + oc) * 16384;
                #pragma unroll
                for (int ntl = 0; ntl < 2; ++ntl) {
                    int tok = (wr * 2 + ntl) * 16 + l15;
                    obase[(y0 + (tok >> 3)) * 128 + x0 + (tok & 7)] = acc[jt][ntl][rr] + pb;
                }
            }
    }
}

// ---- proj kernel (split mode): one output row y per block, full-line writes ----
__global__ __launch_bounds__(256)
void proj_kernel(const char* __restrict__ yb,             // raw [2048][24576]
                 const unsigned short* __restrict__ wp,   // bf16 [192][192]
                 const float* __restrict__ Pb,
                 float* __restrict__ out)
{
    extern __shared__ char smem[];                        // ya[128 px][192 ch] bf16 swizzled
    const int t   = threadIdx.x;
    const int wv  = t >> 6;          // wave 0..3
    const int l15 = t & 15;
    const int l4  = (t >> 4) & 3;

    const int by = blockIdx.x;       // 0..1023
    const int b  = by >> 7;
    const int y  = by & 127;
    const int wy = y >> 3, row = y & 7;

    const f32x4 zz = {0.0f, 0.0f, 0.0f, 0.0f};

    // stage raw swizzled slabs: window wx's toks row*8..row*8+7 = contiguous 3072 B.
    #pragma unroll
    for (int k = 0; k < 12; ++k) {
        int i = t + 256 * k;         // 0..3071 = (px, 16B-chunk cb)
        int px = i / 24, cb = i % 24;
        int wx = px >> 3, col = px & 7;
        const char* src = yb + (size_t)(((b * 16 + wy) * 16 + wx)) * 24576
                        + row * 3072 + col * 384 + cb * 16;
        u32x4 v = __builtin_nontemporal_load((const u32x4*)src);
        *(u32x4*)(smem + px * 384 + cb * 16) = v;
    }
    __syncthreads();

    bf16x8 wfr[3][6];
    #pragma unroll
    for (int jt = 0; jt < 3; ++jt) {
        int oc = wv * 48 + jt * 16;
        const unsigned short* wr_ = wp + (size_t)(oc + l15) * 192 + l4 * 8;
        #pragma unroll
        for (int ks = 0; ks < 6; ++ks) wfr[jt][ks] = gldf(wr_ + ks * 32);
    }
    #pragma unroll
    for (int half = 0; half < 2; ++half) {
        f32x4 acc[3][4];
        #pragma unroll
        for (int jt = 0; jt < 3; ++jt)
            #pragma unroll
            for (int ntl = 0; ntl < 4; ++ntl) acc[jt][ntl] = zz;
        #pragma unroll
        for (int ks = 0; ks < 6; ++ks) {
            bf16x8 bfr[4];
            #pragma unroll
            for (int ntl = 0; ntl < 4; ++ntl) {
                int px = (half * 4 + ntl) * 16 + l15;
                bfr[ntl] = ldsf(smem + ((px * 384 + ks * 64 + l4 * 16) ^ ((px & 7) << 4)));
            }
            #pragma unroll
            for (int jt = 0; jt < 3; ++jt)
                #pragma unroll
                for (int ntl = 0; ntl < 4; ++ntl)
                    acc[jt][ntl] = __builtin_amdgcn_mfma_f32_16x16x32_bf16(wfr[jt][ks], bfr[ntl], acc[jt][ntl], 0, 0, 0);
        }
        #pragma unroll
        for (int jt = 0; jt < 3; ++jt)
            #pragma unroll
            for (int rr = 0; rr < 4; ++rr) {
                int oc = wv * 48 + jt * 16 + l4 * 4 + rr;
                float pb = Pb[oc];
                float* op = out + ((size_t)(b * 192 + oc) * 128 + y) * 128;
                #pragma unroll
                for (int ntl = 0; ntl < 4; ++ntl) {
                    int px = (half * 4 + ntl) * 16 + l15;
                    op[px] = acc[jt][ntl][rr] + pb;
                }
            }
    }
}

extern "C" void kernel_launch(void* const* d_in, const int* in_sizes, int n_in,
                              void* d_out, int out_size, void* d_ws, size_t ws_size,
                              hipStream_t stream) {
    const float* x   = (const float*)d_in[0];
    const float* Vw  = (const float*)d_in[1];
    const float* Vb  = (const float*)d_in[2];
    const float* QKw = (const float*)d_in[3];
    const float* QKb = (const float*)d_in[4];
    const float* Pw  = (const float*)d_in[5];
    const float* Pb  = (const float*)d_in[6];
    const float* Mw1 = (const float*)d_in[7];
    const float* Mb1 = (const float*)d_in[8];
    const float* Mw2 = (const float*)d_in[9];
    const float* Mb2 = (const float*)d_in[10];
    float* outp = (float*)d_out;

    unsigned short* wsb = (unsigned short*)d_ws;               // bf16 weights
    float* b2 = (float*)((char*)d_ws + WS_B2_OFF_B);           // bias2 table
    char* slabs = (char*)d_ws + WS_SLAB_OFF_B;                 // x-in / y-out slabs
    const int split = (ws_size >= (size_t)WS_TOTAL_B) ? 1 : 0;

    prep_kernel<<<dim3(672), dim3(256), 0, stream>>>(QKw, Vw, Pw, Mw1, Mb1, Mw2, Mb2, wsb, b2);
    if (split) {
        (void)hipFuncSetAttribute((const void*)xprep_kernel,
                                  hipFuncAttributeMaxDynamicSharedMemorySize, 98304);
        xprep_kernel<<<dim3(512), dim3(512), 98304, stream>>>(x, slabs);
    }

    (void)hipFuncSetAttribute((const void*)fused_win_attn,
                              hipFuncAttributeMaxDynamicSharedMemorySize, LDS_BYTES);
    fused_win_attn<<<dim3(2048), dim3(512), LDS_BYTES, stream>>>(
        x, Vb, QKb, Pb, wsb, wsb + WS_WP_OFF_EL, b2, slabs, outp, split);

    if (split) {
        (void)hipFuncSetAttribute((const void*)proj_kernel,
                                  hipFuncAttributeMaxDynamicSharedMemorySize, 49152);
        proj_kernel<<<dim3(1024), dim3(256), 49152, stream>>>(
            slabs, wsb + WS_WP_OFF_EL, Pb, outp);
    }
}

// Round 17
// 278.189 us; speedup vs baseline: 1.3754x; 1.0169x over previous
//
#include <hip/hip_runtime.h>

// B=8, C=192, H=W=128, NH=6, HD=32, WS=8, N=64 tokens/window. 2048 windows.
// Round 17: fuse P4+P5 per unit (barrier removed — audit: P5 unit (h,nt) writes
// exactly the RC region that only its own P4 read; v_n/v_t untouched by P5).
// One fewer block-wide barrier + softmax VALU overlaps neighbor-unit PV MFMAs.
#define SCALEQ 0.17677669529663687f   // 32^-0.5

typedef __bf16 bf16x8 __attribute__((ext_vector_type(8)));
typedef __bf16 bf16x2 __attribute__((ext_vector_type(2)));
typedef float f32x4 __attribute__((ext_vector_type(4)));
typedef float f32x2 __attribute__((ext_vector_type(2)));
typedef unsigned int u32x4 __attribute__((ext_vector_type(4)));   // NT-compatible 16B

__device__ __forceinline__ float bflo(unsigned int u) { return __uint_as_float(u << 16); }
__device__ __forceinline__ float bfhi(unsigned int u) { return __uint_as_float(u & 0xffff0000u); }
__device__ __forceinline__ f32x2 b2x2(unsigned int u) {
    f32x2 r; r[0] = bflo(u); r[1] = bfhi(u); return r;
}
// native RNE converts (v_cvt_pk_bf16_f32)
__device__ __forceinline__ unsigned short f2b(float f) {
    return __builtin_bit_cast(unsigned short, (__bf16)f);
}
__device__ __forceinline__ unsigned int pk2(float a, float b) {
    bf16x2 v; v[0] = (__bf16)a; v[1] = (__bf16)b;
    return __builtin_bit_cast(unsigned int, v);
}

// LDS: 3 x 24 KB regions (swizzle byte ^= (row&7)<<4), time-multiplexed:
//  RA 0      xs[64][192] (P1-hoist) | q[64][192] (P2-P3) | v_n[64][192] (P3b-P45)
//  RB 24576  k[64][192]  (P2-P3)    | v_t[192][64] (P3b-P45)
//  RC 49152  o[64][192]  (P3-P45)   | y[64][192]  (P45-)
#define RA     0
#define RB     24576
#define RC     49152
#define LDS_BYTES 73728

// d_ws layout (bytes):
//  [0]      qkv weights bf16 [576][192] (q rows pre-scaled)   221184 B
//  [221184] proj weights bf16 [192][192]                       73728 B
//  [294912] bias2 f32 [6][64][64]                              98304 B
//  [393216] slab buffer [2048][24576 B]: xprep writes x-slabs; fused reads slab
//           wid at P1 then overwrites it with y at P5b; proj reads y slabs.
#define WS_WQKV_ELEMS 110592
#define WS_WP_OFF_EL  110592
#define WS_B2_OFF_B   294912
#define WS_SLAB_OFF_B 393216
#define WS_TOTAL_B    50724864

__device__ __forceinline__ bf16x8 ldsf(const char* p) {
    u32x4 u = *(const u32x4*)p;
    return __builtin_bit_cast(bf16x8, u);
}
__device__ __forceinline__ bf16x8 gldf(const unsigned short* p) {
    u32x4 u = *(const u32x4*)p;
    return __builtin_bit_cast(bf16x8, u);
}

// ---- prep kernel: weights f32->bf16 (q pre-scaled) + bias2 table. 672 blocks ----
__global__ void prep_kernel(const float* __restrict__ QKw, const float* __restrict__ Vw,
                            const float* __restrict__ Pw,
                            const float* __restrict__ Mw1, const float* __restrict__ Mb1,
                            const float* __restrict__ Mw2, const float* __restrict__ Mb2,
                            unsigned short* __restrict__ wsb, float* __restrict__ b2) {
    int gid = blockIdx.x * 256 + threadIdx.x;      // 0 .. 172031
    if (gid < WS_WQKV_ELEMS) {
        int r = gid / 192, c = gid - r * 192;
        float v = (r < 384) ? QKw[r * 192 + c] : Vw[(r - 384) * 192 + c];
        if (r < 192) v *= SCALEQ;
        wsb[gid] = f2b(v);
    } else if (gid < 147456) {
        int j = gid - WS_WQKV_ELEMS;
        wsb[WS_WP_OFF_EL + j] = f2b(Pw[j]);
    } else {
        int i = gid - 147456;                       // 0 .. 24575
        int h = i >> 12, n = (i >> 6) & 63, m = i & 63;
        float dy = (float)((n >> 3) - (m >> 3));
        float dx = (float)((n & 7) - (m & 7));
        float f0 = copysignf(log1pf(fabsf(dy)), dy);
        float f1 = copysignf(log1pf(fabsf(dx)), dx);
        float a = Mb2[h];
        for (int u = 0; u < 256; ++u) {
            float hv = fmaxf(f0 * Mw1[u] + f1 * Mw1[256 + u] + Mb1[u], 0.0f);
            a = fmaf(hv, Mw2[u * 6 + h], a);
        }
        b2[i] = a;
    }
}

// ---- xprep: x fp32 -> bf16 window slabs via LDS staging, NT full-line writes ----
// block = (b, wy, wxg): 4 wx-adjacent windows. 512 threads, 96 KB dynamic LDS.
__global__ __launch_bounds__(512)
void xprep_kernel(const float* __restrict__ x, char* __restrict__ xw) {
    extern __shared__ char lsm[];          // 4 slab images, 24576 B each
    const int t = threadIdx.x;
    const int blk = blockIdx.x;            // 0..511
    const int b = blk >> 6, wy = (blk >> 2) & 15, wxg = blk & 3;
    const float* xb = x + (size_t)b * 192 * 16384;

    // load: 12288 float4 / 512 thr = 24 iters; lanes 0..7 cover one row's 32 px
    #pragma unroll 4
    for (int i = 0; i < 24; ++i) {
        int idx = t + 512 * i;             // 0..12287
        int c = idx >> 6, rem = idx & 63;
        int r = rem >> 3, g = rem & 7;     // g = float4 group within 32 px
        float4 v4 = *(const float4*)(xb + c * 16384 + (wy * 8 + r) * 128 + wxg * 32 + g * 4);
        int s  = g >> 1;                   // slab (window) within block
        char* slab = lsm + s * 24576;
        int n0 = r * 8 + (g & 1) * 4;
        unsigned short sv[4] = {f2b(v4.x), f2b(v4.y), f2b(v4.z), f2b(v4.w)};
        #pragma unroll
        for (int e = 0; e < 4; ++e) {
            int n = n0 + e;
            *(unsigned short*)(slab + ((n * 384 + c * 2) ^ ((n & 7) << 4))) = sv[e];
        }
    }
    __syncthreads();

    // store: 4 slabs x 1536 u32x4, contiguous full-line NT streams
    #pragma unroll
    for (int s = 0; s < 4; ++s) {
        int wid = (b << 8) | (wy << 4) | (wxg * 4 + s);
        char* dst = xw + (size_t)wid * 24576;
        const char* src = lsm + s * 24576;
        #pragma unroll
        for (int j = 0; j < 3; ++j) {
            int ch = t + 512 * j;          // 0..1535
            u32x4 v = *(const u32x4*)(src + ch * 16);
            __builtin_nontemporal_store(v, (u32x4*)(dst + ch * 16));
        }
    }
}

__global__ __launch_bounds__(512, 4)
void fused_win_attn(const float* __restrict__ x,
                    const float* __restrict__ Vb, const float* __restrict__ QKb,
                    const float* __restrict__ Pb,
                    const unsigned short* __restrict__ wqkv,   // bf16 [576][192]
                    const unsigned short* __restrict__ wp,     // bf16 [192][192]
                    const float* __restrict__ bias2,           // f32 [6][64][64]
                    char* __restrict__ slabs,                  // [2048][24576] x-in / y-out
                    float* __restrict__ out,
                    int split)
{
    extern __shared__ char smem[];
    const int t   = threadIdx.x;
    const int wv  = t >> 6;           // wave 0..7
    const int l15 = t & 15;
    const int l4  = (t >> 4) & 3;

    const int wid = ((blockIdx.x & 7) << 8) | (blockIdx.x >> 3);
    const int b   = wid >> 8;
    const int wy  = (wid >> 4) & 15;
    const int wx  = wid & 15;
    const int y0  = wy * 8, x0 = wx * 8;

    const f32x4 zz = {0.0f, 0.0f, 0.0f, 0.0f};

    // ---- P1: stage x slab -> RA (NT loads: single-use stream) ----
    if (split) {
        const char* slab = slabs + (size_t)wid * 24576;
        #pragma unroll
        for (int i = 0; i < 3; ++i) {
            int idx = t + 512 * i;               // 1536 u32x4 chunks
            u32x4 v = __builtin_nontemporal_load((const u32x4*)(slab + idx * 16));
            *(u32x4*)(smem + RA + idx * 16) = v;
        }
    } else {
        const float* xb = x + (size_t)b * 192 * 16384;
        #pragma unroll
        for (int i = 0; i < 6; ++i) {
            int idx = t + 512 * i;
            int c = idx >> 4, sub = idx & 15;
            int r = sub >> 1, hf = sub & 1;
            float4 v4 = *(const float4*)(xb + c * 16384 + (y0 + r) * 128 + x0 + hf * 4);
            int n0 = r * 8 + hf * 4;
            unsigned short sv[4] = {f2b(v4.x), f2b(v4.y), f2b(v4.z), f2b(v4.w)};
            #pragma unroll
            for (int e = 0; e < 4; ++e) {
                int n = n0 + e;
                *(unsigned short*)(smem + RA + ((n * 384 + c * 2) ^ ((n & 7) << 4))) = sv[e];
            }
        }
    }
    __syncthreads();

    // ---- P2: qkv GEMM. wave (wcol, wrow): cols [48*wcol,+48) per tensor, toks [32*wrow,+32) ----
    const int wcol = wv & 3, wrow = wv >> 2;
    unsigned int vp[3][2][2];          // packed v held across conv: [j][mtl][tok-pair]
    {
        bf16x8 afr[6][2];
        #pragma unroll
        for (int ks = 0; ks < 6; ++ks)
            #pragma unroll
            for (int mtl = 0; mtl < 2; ++mtl) {
                int row = (wrow * 2 + mtl) * 16 + l15;
                afr[ks][mtl] = ldsf(smem + RA + ((row * 384 + ks * 64 + l4 * 16) ^ ((row & 7) << 4)));
            }
        __syncthreads();

        auto gemm3 = [&](int obase, f32x4 acc[3][2]) {
            bf16x8 bw[3][6];
            #pragma unroll
            for (int j = 0; j < 3; ++j) {
                const unsigned short* wr = wqkv + (size_t)(obase + j * 16 + l15) * 192 + l4 * 8;
                #pragma unroll
                for (int ks = 0; ks < 6; ++ks) bw[j][ks] = gldf(wr + ks * 32);
            }
            #pragma unroll
            for (int j = 0; j < 3; ++j) { acc[j][0] = zz; acc[j][1] = zz; }
            #pragma unroll
            for (int ks = 0; ks < 6; ++ks)
                #pragma unroll
                for (int j = 0; j < 3; ++j)
                    #pragma unroll
                    for (int mtl = 0; mtl < 2; ++mtl)
                        acc[j][mtl] = __builtin_amdgcn_mfma_f32_16x16x32_bf16(afr[ks][mtl], bw[j][ks], acc[j][mtl], 0, 0, 0);
        };

        // chunk 0: q -> region A (weights pre-scaled; bias scaled here)
        {
            f32x4 acc[3][2];
            gemm3(wcol * 48, acc);
            #pragma unroll
            for (int j = 0; j < 3; ++j) {
                int och = wcol * 48 + j * 16 + l15;
                float bv = QKb[och] * SCALEQ;
                #pragma unroll
                for (int mtl = 0; mtl < 2; ++mtl)
                    #pragma unroll
                    for (int rr = 0; rr < 4; ++rr) {
                        int tok = (wrow * 2 + mtl) * 16 + l4 * 4 + rr;
                        *(unsigned short*)(smem + RA + ((tok * 384 + och * 2) ^ ((tok & 7) << 4)))
                            = f2b(acc[j][mtl][rr] + bv);
                    }
            }
        }
        // chunk 1: k -> region B
        {
            f32x4 acc[3][2];
            gemm3(192 + wcol * 48, acc);
            #pragma unroll
            for (int j = 0; j < 3; ++j) {
                int ch = wcol * 48 + j * 16 + l15;
                float bv = QKb[192 + ch];
                #pragma unroll
                for (int mtl = 0; mtl < 2; ++mtl)
                    #pragma unroll
                    for (int rr = 0; rr < 4; ++rr) {
                        int tok = (wrow * 2 + mtl) * 16 + l4 * 4 + rr;
                        *(unsigned short*)(smem + RB + ((tok * 384 + ch * 2) ^ ((tok & 7) << 4)))
                            = f2b(acc[j][mtl][rr] + bv);
                    }
            }
        }
        // chunk 2: v -> registers (packed bf16 pairs along tok)
        {
            f32x4 acc[3][2];
            gemm3(384 + wcol * 48, acc);
            #pragma unroll
            for (int j = 0; j < 3; ++j) {
                int ch = wcol * 48 + j * 16 + l15;
                float bv = Vb[ch];
                #pragma unroll
                for (int mtl = 0; mtl < 2; ++mtl) {
                    vp[j][mtl][0] = pk2(acc[j][mtl][0] + bv, acc[j][mtl][1] + bv);
                    vp[j][mtl][1] = pk2(acc[j][mtl][2] + bv, acc[j][mtl][3] + bv);
                }
            }
        }
    }
    __syncthreads();

    // ---- P3: 8x8 circular conv q(A) x k(B) -> o(C). 384 threads, f32x2 packed ----
    if (t < 384) {
        const int rn = t / 48, cc = t % 48;
        const int c0b = cc * 8;               // byte offset of 4-ch chunk
        f32x2 acc[8][2];
        #pragma unroll
        for (int cn = 0; cn < 8; ++cn) {
            acc[cn][0] = (f32x2){0.0f, 0.0f};
            acc[cn][1] = (f32x2){0.0f, 0.0f};
        }
        #pragma unroll
        for (int kh = 0; kh < 2; ++kh) {
            uint2 karr[32];
            #pragma unroll
            for (int m = 0; m < 32; ++m) {
                int row = kh * 32 + m;
                karr[m] = *(const uint2*)(smem + RB + ((row * 384 + c0b) ^ ((row & 7) << 4)));
            }
            #pragma unroll
            for (int mrl = 0; mrl < 4; ++mrl) {
                const int mr = kh * 4 + mrl;
                f32x2 kf[8][2];
                #pragma unroll
                for (int mc = 0; mc < 8; ++mc) {
                    uint2 kv = karr[mrl * 8 + mc];
                    kf[mc][0] = b2x2(kv.x); kf[mc][1] = b2x2(kv.y);
                }
                const int npr = (rn - mr) & 7;
                #pragma unroll
                for (int npc = 0; npc < 8; ++npc) {
                    int np = npr * 8 + npc;
                    uint2 qv = *(const uint2*)(smem + RA + ((np * 384 + c0b) ^ ((np & 7) << 4)));
                    f32x2 qf0 = b2x2(qv.x), qf1 = b2x2(qv.y);
                    #pragma unroll
                    for (int mc = 0; mc < 8; ++mc) {
                        int cn = (npc + mc) & 7;
                        acc[cn][0] = qf0 * kf[mc][0] + acc[cn][0];
                        acc[cn][1] = qf1 * kf[mc][1] + acc[cn][1];
                    }
                }
            }
        }
        #pragma unroll
        for (int cn = 0; cn < 8; ++cn) {
            int n = rn * 8 + cn;
            uint2 pk;
            pk.x = pk2(acc[cn][0][0], acc[cn][0][1]);
            pk.y = pk2(acc[cn][1][0], acc[cn][1][1]);
            *(uint2*)(smem + RC + ((n * 384 + c0b) ^ ((n & 7) << 4))) = pk;
        }
    }
    __syncthreads();

    // ---- P3b: write held v regs -> v_n (A, over q) and v_t (B, over k) ----
    {
        #pragma unroll
        for (int j = 0; j < 3; ++j) {
            int ch = wcol * 48 + j * 16 + l15;
            #pragma unroll
            for (int mtl = 0; mtl < 2; ++mtl)
                #pragma unroll
                for (int pp = 0; pp < 2; ++pp) {
                    unsigned int pk = vp[j][mtl][pp];
                    int tok0 = (wrow * 2 + mtl) * 16 + l4 * 4 + pp * 2;
                    *(unsigned int*)(smem + RB + ((ch * 128 + tok0 * 2) ^ ((ch & 7) << 4))) = pk;
                    *(unsigned short*)(smem + RA + ((tok0 * 384 + ch * 2) ^ ((tok0 & 7) << 4)))
                        = (unsigned short)(pk & 0xffffu);
                    *(unsigned short*)(smem + RA + (((tok0 + 1) * 384 + ch * 2) ^ (((tok0 + 1) & 7) << 4)))
                        = (unsigned short)(pk >> 16);
                }
        }
    }
    __syncthreads();

    // ---- P4+P5 fused per unit: S^T = mfma(v_n,o)+bias2, softmax, Y = mfma(P,v_t).
    // No barrier between: P5 unit (h,nt) writes RC rows[16nt,+16) x bytes[64h,+64),
    // exactly and only the region its own P4 read as o; v_n/v_t are read-only here.
    {
        #pragma unroll
        for (int i = 0; i < 3; ++i) {
            int u = wv * 3 + i;
            int h = u >> 2, nt = u & 3;
            // --- P4 part: scores + softmax -> packed P (per-unit local) ---
            int brow = nt * 16 + l15;
            bf16x8 ofr = ldsf(smem + RC + ((brow * 384 + h * 64 + l4 * 16) ^ ((brow & 7) << 4)));
            int n = nt * 16 + l15;
            const float* bp = bias2 + ((h * 64 + n) << 6) + l4 * 4;
            float s[4][4];
            #pragma unroll
            for (int mt = 0; mt < 4; ++mt) {
                int arow = mt * 16 + l15;
                bf16x8 vfr = ldsf(smem + RA + ((arow * 384 + h * 64 + l4 * 16) ^ ((arow & 7) << 4)));
                f32x4 a = __builtin_amdgcn_mfma_f32_16x16x32_bf16(vfr, ofr, zz, 0, 0, 0);
                float4 bb = *(const float4*)(bp + mt * 16);
                s[mt][0] = a[0] + bb.x; s[mt][1] = a[1] + bb.y;
                s[mt][2] = a[2] + bb.z; s[mt][3] = a[3] + bb.w;
            }
            float m0 = s[0][0];
            #pragma unroll
            for (int mt = 0; mt < 4; ++mt)
                #pragma unroll
                for (int rr = 0; rr < 4; ++rr) m0 = fmaxf(m0, s[mt][rr]);
            m0 = fmaxf(m0, __shfl_xor(m0, 16));
            m0 = fmaxf(m0, __shfl_xor(m0, 32));
            float sm = 0.0f;
            #pragma unroll
            for (int mt = 0; mt < 4; ++mt)
                #pragma unroll
                for (int rr = 0; rr < 4; ++rr) {
                    float p = __expf(s[mt][rr] - m0);
                    s[mt][rr] = p; sm += p;
                }
            sm += __shfl_xor(sm, 16);
            sm += __shfl_xor(sm, 32);
            float inv = 1.0f / sm;
            unsigned int pvU[4][2];
            #pragma unroll
            for (int mt = 0; mt < 4; ++mt) {
                pvU[mt][0] = pk2(s[mt][0] * inv, s[mt][1] * inv);
                pvU[mt][1] = pk2(s[mt][2] * inv, s[mt][3] * inv);
            }
            // --- P5 part: redistribute P, PV MFMA, write y over this unit's o ---
            bf16x8 pafr[2];
            #pragma unroll
            for (int ks = 0; ks < 2; ++ks) {
                unsigned int au[4];
                #pragma unroll
                for (int p = 0; p < 4; ++p) {
                    int srcl4 = (2 * l4 + (p >> 1)) & 3;
                    int src = srcl4 * 16 + l15;
                    unsigned int v0 = (unsigned int)__shfl((int)pvU[2 * ks][p & 1], src, 64);
                    unsigned int v1 = (unsigned int)__shfl((int)pvU[2 * ks + 1][p & 1], src, 64);
                    au[p] = (l4 & 2) ? v1 : v0;
                }
                u32x4 u4 = {au[0], au[1], au[2], au[3]};
                pafr[ks] = __builtin_bit_cast(bf16x8, u4);
            }
            f32x4 acc[2];
            acc[0] = zz; acc[1] = zz;
            #pragma unroll
            for (int dt = 0; dt < 2; ++dt)
                #pragma unroll
                for (int ks = 0; ks < 2; ++ks) {
                    int drow = h * 32 + dt * 16 + l15;
                    bf16x8 vtf = ldsf(smem + RB + ((drow * 128 + ks * 64 + l4 * 16) ^ ((drow & 7) << 4)));
                    acc[dt] = __builtin_amdgcn_mfma_f32_16x16x32_bf16(pafr[ks], vtf, acc[dt], 0, 0, 0);
                }
            #pragma unroll
            for (int dt = 0; dt < 2; ++dt)
                #pragma unroll
                for (int rr = 0; rr < 4; ++rr) {
                    int tok = nt * 16 + l4 * 4 + rr;
                    int ch  = h * 32 + dt * 16 + l15;
                    *(unsigned short*)(smem + RC + ((tok * 384 + ch * 2) ^ ((tok & 7) << 4))) = f2b(acc[dt][rr]);
                }
        }
    }
    __syncthreads();

    if (split) {
        // ---- P5b: raw copy RC (24 KB, swizzled) -> slab wid, NT full-line ----
        char* ybw = slabs + (size_t)wid * 24576;
        #pragma unroll
        for (int c = 0; c < 3; ++c) {
            int idx = t + 512 * c;               // 0..1535 u32x4 chunks
            u32x4 v = *(const u32x4*)(smem + RC + idx * 16);
            __builtin_nontemporal_store(v, (u32x4*)(ybw + idx * 16));
        }
        return;
    }

    // ---- P6 (fallback only): proj OUT^T[oc][tok] = Pw . y^T ----
    {
        const int wc = wv & 3, wr = wv >> 2;
        bf16x8 wfr[3][6];
        #pragma unroll
        for (int jt = 0; jt < 3; ++jt) {
            int oc = wc * 48 + jt * 16;
            const unsigned short* wr_ = wp + (size_t)(oc + l15) * 192 + l4 * 8;
            #pragma unroll
            for (int ks = 0; ks < 6; ++ks) wfr[jt][ks] = gldf(wr_ + ks * 32);
        }
        f32x4 acc[3][2];
        #pragma unroll
        for (int jt = 0; jt < 3; ++jt) { acc[jt][0] = zz; acc[jt][1] = zz; }

        #pragma unroll
        for (int ks = 0; ks < 6; ++ks) {
            bf16x8 bfr[2];
            #pragma unroll
            for (int ntl = 0; ntl < 2; ++ntl) {
                int tok = (wr * 2 + ntl) * 16 + l15;
                bfr[ntl] = ldsf(smem + RC + ((tok * 384 + ks * 64 + l4 * 16) ^ ((tok & 7) << 4)));
            }
            #pragma unroll
            for (int jt = 0; jt < 3; ++jt)
                #pragma unroll
                for (int ntl = 0; ntl < 2; ++ntl)
                    acc[jt][ntl] = __builtin_amdgcn_mfma_f32_16x16x32_bf16(wfr[jt][ks], bfr[ntl], acc[jt][ntl], 0, 0, 0);
        }
        #pragma unroll
        for (int jt = 0; jt < 3; ++jt)
            #pragma unroll
            for (int rr = 0; rr < 4; ++rr) {
                int oc = wc * 48 + jt * 16 + l4 * 4 + rr;
                float pb = Pb[oc];
                float* obase = out + (size_t)(b * 192 + oc) * 16384;
                #pragma unroll
                for (int ntl = 0; ntl < 2; ++ntl) {
                    int tok = (wr * 2 + ntl) * 16 + l15;
                    obase[(y0 + (tok >> 3)) * 128 + x0 + (tok & 7)] = acc[jt][ntl][rr] + pb;
                }
            }
    }
}

// ---- proj kernel (split mode): one output row y per block, full-line writes ----
__global__ __launch_bounds__(256)
void proj_kernel(const char* __restrict__ yb,             // raw [2048][24576]
                 const unsigned short* __restrict__ wp,   // bf16 [192][192]
                 const float* __restrict__ Pb,
                 float* __restrict__ out)
{
    extern __shared__ char smem[];                        // ya[128 px][192 ch] bf16 swizzled
    const int t   = threadIdx.x;
    const int wv  = t >> 6;          // wave 0..3
    const int l15 = t & 15;
    const int l4  = (t >> 4) & 3;

    const int by = blockIdx.x;       // 0..1023
    const int b  = by >> 7;
    const int y  = by & 127;
    const int wy = y >> 3, row = y & 7;

    const f32x4 zz = {0.0f, 0.0f, 0.0f, 0.0f};

    // stage raw swizzled slabs: window wx's toks row*8..row*8+7 = contiguous 3072 B.
    #pragma unroll
    for (int k = 0; k < 12; ++k) {
        int i = t + 256 * k;         // 0..3071 = (px, 16B-chunk cb)
        int px = i / 24, cb = i % 24;
        int wx = px >> 3, col = px & 7;
        const char* src = yb + (size_t)(((b * 16 + wy) * 16 + wx)) * 24576
                        + row * 3072 + col * 384 + cb * 16;
        u32x4 v = __builtin_nontemporal_load((const u32x4*)src);
        *(u32x4*)(smem + px * 384 + cb * 16) = v;
    }
    __syncthreads();

    bf16x8 wfr[3][6];
    #pragma unroll
    for (int jt = 0; jt < 3; ++jt) {
        int oc = wv * 48 + jt * 16;
        const unsigned short* wr_ = wp + (size_t)(oc + l15) * 192 + l4 * 8;
        #pragma unroll
        for (int ks = 0; ks < 6; ++ks) wfr[jt][ks] = gldf(wr_ + ks * 32);
    }
    #pragma unroll
    for (int half = 0; half < 2; ++half) {
        f32x4 acc[3][4];
        #pragma unroll
        for (int jt = 0; jt < 3; ++jt)
            #pragma unroll
            for (int ntl = 0; ntl < 4; ++ntl) acc[jt][ntl] = zz;
        #pragma unroll
        for (int ks = 0; ks < 6; ++ks) {
            bf16x8 bfr[4];
            #pragma unroll
            for (int ntl = 0; ntl < 4; ++ntl) {
                int px = (half * 4 + ntl) * 16 + l15;
                bfr[ntl] = ldsf(smem + ((px * 384 + ks * 64 + l4 * 16) ^ ((px & 7) << 4)));
            }
            #pragma unroll
            for (int jt = 0; jt < 3; ++jt)
                #pragma unroll
                for (int ntl = 0; ntl < 4; ++ntl)
                    acc[jt][ntl] = __builtin_amdgcn_mfma_f32_16x16x32_bf16(wfr[jt][ks], bfr[ntl], acc[jt][ntl], 0, 0, 0);
        }
        #pragma unroll
        for (int jt = 0; jt < 3; ++jt)
            #pragma unroll
            for (int rr = 0; rr < 4; ++rr) {
                int oc = wv * 48 + jt * 16 + l4 * 4 + rr;
                float pb = Pb[oc];
                float* op = out + ((size_t)(b * 192 + oc) * 128 + y) * 128;
                #pragma unroll
                for (int ntl = 0; ntl < 4; ++ntl) {
                    int px = (half * 4 + ntl) * 16 + l15;
                    op[px] = acc[jt][ntl][rr] + pb;
                }
            }
    }
}

extern "C" void kernel_launch(void* const* d_in, const int* in_sizes, int n_in,
                              void* d_out, int out_size, void* d_ws, size_t ws_size,
                              hipStream_t stream) {
    const float* x   = (const float*)d_in[0];
    const float* Vw  = (const float*)d_in[1];
    const float* Vb  = (const float*)d_in[2];
    const float* QKw = (const float*)d_in[3];
    const float* QKb = (const float*)d_in[4];
    const float* Pw  = (const float*)d_in[5];
    const float* Pb  = (const float*)d_in[6];
    const float* Mw1 = (const float*)d_in[7];
    const float* Mb1 = (const float*)d_in[8];
    const float* Mw2 = (const float*)d_in[9];
    const float* Mb2 = (const float*)d_in[10];
    float* outp = (float*)d_out;

    unsigned short* wsb = (unsigned short*)d_ws;               // bf16 weights
    float* b2 = (float*)((char*)d_ws + WS_B2_OFF_B);           // bias2 table
    char* slabs = (char*)d_ws + WS_SLAB_OFF_B;                 // x-in / y-out slabs
    const int split = (ws_size >= (size_t)WS_TOTAL_B) ? 1 : 0;

    prep_kernel<<<dim3(672), dim3(256), 0, stream>>>(QKw, Vw, Pw, Mw1, Mb1, Mw2, Mb2, wsb, b2);
    if (split) {
        (void)hipFuncSetAttribute((const void*)xprep_kernel,
                                  hipFuncAttributeMaxDynamicSharedMemorySize, 98304);
        xprep_kernel<<<dim3(512), dim3(512), 98304, stream>>>(x, slabs);
    }

    (void)hipFuncSetAttribute((const void*)fused_win_attn,
                              hipFuncAttributeMaxDynamicSharedMemorySize, LDS_BYTES);
    fused_win_attn<<<dim3(2048), dim3(512), LDS_BYTES, stream>>>(
        x, Vb, QKb, Pb, wsb, wsb + WS_WP_OFF_EL, b2, slabs, outp, split);

    if (split) {
        (void)hipFuncSetAttribute((const void*)proj_kernel,
                                  hipFuncAttributeMaxDynamicSharedMemorySize, 49152);
        proj_kernel<<<dim3(1024), dim3(256), 49152, stream>>>(
            slabs, wsb + WS_WP_OFF_EL, Pb, outp);
    }
}